// Round 2
// baseline (658.554 us; speedup 1.0000x reference)
//
#include <hip/hip_runtime.h>

// ---------------------------------------------------------------------------
// EquivariantProductBasisBlock (MACE symmetric contraction + gate + linear)
// N=10000 nodes, C=128 channels, D=9 (0e+1o+2e), S=10 species.
// R2: k_contract rewritten — j-loop fully unrolled (register x), 8 nodes per
// thread (DS-pipe budget), LDS = rec only (15.7 KB), select-chain for x[i].
// ---------------------------------------------------------------------------

#define NN 10000
#define CC 128
#define SS 10
#define NPB 1024                 // nodes per contraction segment
#define MAXBLK 20                // >= floor(N/NPB)+S = 9+10
#define NPAD (MAXBLK*NPB)        // 20480 padded positions
#define MM 8                     // nodes per thread in k_contract

// per-(c,s) record layout (floats):
//  [0,2916)   : 1o  [z][i][j][12] ; k=0..8 -> U3w_1o, [9]=U2w_1o, [10..11]=0
//  [2916,2944): U1w_1o [z][i] (27) + pad
//  [2944,3916): 0e  [i][j][12]   ; k=0..8 -> U3w_0e, [9]=U2w_0e
//  [3916,3928): U1w_0e [i] (9) + pad
#define U1_1O 2916
#define R0E   2944
#define U1_0E 3916
#define REC   3928

// ws layout (floats)
#define OFF_UW   0                         // CC*SS*REC = 5,027,840
#define OFF_F0   5027840                   // CC*NPAD   = 2,621,440
#define OFF_F1   7649280                   // 3*CC*NPAD = 7,864,320
#define OFF_GATE 15513600                  // NPAD*256  = 5,242,880
#define OFF_ORD  20756480                  // NPAD ints
#define OFF_META (OFF_ORD + NPAD)          // 64 ints
// total = 20,777,024 floats = 83.1 MB

// ---------------- species bucketing ----------------
__global__ void k_hist(const int* __restrict__ sp, int* __restrict__ counts) {
    int n = blockIdx.x * 256 + threadIdx.x;
    if (n < NN) atomicAdd(&counts[sp[n]], 1);
}

__global__ void k_plan(const int* __restrict__ counts, int* __restrict__ cursor,
                       int* __restrict__ blk_sp) {
    if (threadIdx.x != 0) return;
    int pos = 0, b = 0;
    for (int s = 0; s < SS; ++s) {
        cursor[s] = pos;
        int nb = (counts[s] + NPB - 1) / NPB;
        for (int i = 0; i < nb; ++i) blk_sp[b++] = s;
        pos += nb * NPB;
    }
    for (; b < MAXBLK; ++b) blk_sp[b] = -1;
}

__global__ void k_scatter(const int* __restrict__ sp, int* __restrict__ cursor,
                          int* __restrict__ order) {
    int n = blockIdx.x * 256 + threadIdx.x;
    if (n < NN) {
        int p = atomicAdd(&cursor[sp[n]], 1);
        order[p] = n;
    }
}

// ---------------- precompute U*w records ----------------
__global__ __launch_bounds__(256) void k_prep(
    const float* __restrict__ u1_0e, const float* __restrict__ u2_0e, const float* __restrict__ u3_0e,
    const float* __restrict__ u1_1o, const float* __restrict__ u2_1o, const float* __restrict__ u3_1o,
    const float* __restrict__ w1_0e, const float* __restrict__ w2_0e, const float* __restrict__ w3_0e,
    const float* __restrict__ w1_1o, const float* __restrict__ w2_1o, const float* __restrict__ w3_1o,
    float* __restrict__ uw) {
    int b = blockIdx.x;            // b = c*SS + s
    int c = b / SS, s = b % SS;
    float* rec = uw + (size_t)b * REC;
    for (int idx = threadIdx.x; idx < REC; idx += 256) {
        float v = 0.f;
        if (idx < 2916) {
            int q = idx / 12, k = idx % 12;        // q = (z*9+i)*9+j
            if (k < 9) {
                const float* u = u3_1o + (q * 9 + k) * 30;
                const float* w = w3_1o + s * 30 * CC + c;
                float a = 0.f;
                for (int p = 0; p < 30; ++p) a += u[p] * w[p * CC];
                v = a;
            } else if (k == 9) {
                const float* u = u2_1o + q * 4;
                const float* w = w2_1o + s * 4 * CC + c;
                float a = 0.f;
                for (int p = 0; p < 4; ++p) a += u[p] * w[p * CC];
                v = a;
            }
        } else if (idx < R0E) {
            int e = idx - U1_1O;                   // [z][i]
            if (e < 27) v = u1_1o[e] * w1_1o[s * CC + c];
        } else if (idx < U1_0E) {
            int e = idx - R0E;
            int q = e / 12, k = e % 12;            // q = i*9+j
            if (k < 9) {
                const float* u = u3_0e + (q * 9 + k) * 23;
                const float* w = w3_0e + s * 23 * CC + c;
                float a = 0.f;
                for (int p = 0; p < 23; ++p) a += u[p] * w[p * CC];
                v = a;
            } else if (k == 9) {
                const float* u = u2_0e + q * 4;
                const float* w = w2_0e + s * 4 * CC + c;
                float a = 0.f;
                for (int p = 0; p < 4; ++p) a += u[p] * w[p * CC];
                v = a;
            }
        } else {
            int e = idx - U1_0E;
            if (e < 9) v = u1_0e[e] * w1_0e[s * CC + c];
        }
        rec[idx] = v;
    }
}

// ---------------- symmetric contraction ----------------
// 128 threads x MM=8 nodes = 1024 nodes per block; j fully unrolled so x[m][j]
// is a static register; only x[m][i] needs a select chain (i dynamic).
__global__ __launch_bounds__(128, 2) void k_contract(
    const float* __restrict__ nf, const int* __restrict__ order,
    const int* __restrict__ blk_sp, const float* __restrict__ uw,
    float* __restrict__ f0t, float* __restrict__ f1t) {
    int b = blockIdx.x, c = blockIdx.y;
    int s = blk_sp[b];
    if (s < 0) return;                 // block-uniform exit
    __shared__ float rec[REC];

    int tid = threadIdx.x;
    int pos0 = b * NPB + tid * MM;

    // stage the (c,s) record (issue early; barrier below)
    const float* src = uw + (size_t)(c * SS + s) * REC;
    for (int i = tid * 4; i < REC; i += 512)
        *(float4*)&rec[i] = *(const float4*)&src[i];

    // per-thread 8 nodes (segment is species-uniform)
    float x[MM][9];
#pragma unroll
    for (int m = 0; m < MM; ++m) {
        int n = order[pos0 + m];
        if (n >= 0) {
            const float* r = nf + (size_t)n * 1152;
            x[m][0] = r[c];
#pragma unroll
            for (int j = 0; j < 3; ++j) x[m][1 + j] = r[128 + c * 3 + j];
#pragma unroll
            for (int j = 0; j < 5; ++j) x[m][4 + j] = r[512 + c * 5 + j];
        } else {
#pragma unroll
            for (int k = 0; k < 9; ++k) x[m][k] = 0.f;
        }
    }

    __syncthreads();

    float o0[MM];
    float o1[MM][3];
#pragma unroll
    for (int m = 0; m < MM; ++m) {
        o0[m] = 0.f;
        o1[m][0] = 0.f; o1[m][1] = 0.f; o1[m][2] = 0.f;
    }

#pragma unroll 1
    for (int i = 0; i < 9; ++i) {
        // x[m][i] with dynamic i: 8-deep select chain (cheap vs ~2900 FMAs/iter)
        float xi[MM];
#pragma unroll
        for (int m = 0; m < MM; ++m) {
            float v = x[m][0];
#pragma unroll
            for (int im = 1; im < 9; ++im) v = (i == im) ? x[m][im] : v;
            xi[m] = v;
        }

        // ---- 1o (z = 0..2) ----
#pragma unroll
        for (int z = 0; z < 3; ++z) {
            float B[MM];
#pragma unroll
            for (int m = 0; m < MM; ++m) B[m] = 0.f;
#pragma unroll
            for (int j = 0; j < 9; ++j) {
                const float* row = &rec[z * 972 + i * 108 + j * 12];
                float4 a  = *(const float4*)row;
                float4 bq = *(const float4*)(row + 4);
                float4 cq = *(const float4*)(row + 8);
#pragma unroll
                for (int m = 0; m < MM; ++m) {
                    float t = cq.y;                       // U2w
                    t += a.x * x[m][0]; t += a.y * x[m][1];
                    t += a.z * x[m][2]; t += a.w * x[m][3];
                    t += bq.x * x[m][4]; t += bq.y * x[m][5];
                    t += bq.z * x[m][6]; t += bq.w * x[m][7];
                    t += cq.x * x[m][8];
                    B[m] += t * x[m][j];                  // static j!
                }
            }
            float u1 = rec[U1_1O + z * 9 + i];
#pragma unroll
            for (int m = 0; m < MM; ++m) o1[m][z] += (u1 + B[m]) * xi[m];
        }

        // ---- 0e ----
        {
            float B[MM];
#pragma unroll
            for (int m = 0; m < MM; ++m) B[m] = 0.f;
#pragma unroll
            for (int j = 0; j < 9; ++j) {
                const float* row = &rec[R0E + i * 108 + j * 12];
                float4 a  = *(const float4*)row;
                float4 bq = *(const float4*)(row + 4);
                float4 cq = *(const float4*)(row + 8);
#pragma unroll
                for (int m = 0; m < MM; ++m) {
                    float t = cq.y;
                    t += a.x * x[m][0]; t += a.y * x[m][1];
                    t += a.z * x[m][2]; t += a.w * x[m][3];
                    t += bq.x * x[m][4]; t += bq.y * x[m][5];
                    t += bq.z * x[m][6]; t += bq.w * x[m][7];
                    t += cq.x * x[m][8];
                    B[m] += t * x[m][j];
                }
            }
            float u1 = rec[U1_0E + i];
#pragma unroll
            for (int m = 0; m < MM; ++m) o0[m] += (u1 + B[m]) * xi[m];
        }
    }

    // coalesced stores in sorted-position space (8 consecutive floats/thread)
#pragma unroll
    for (int h = 0; h < MM; h += 4) {
        float4 v0 = {o0[h], o0[h + 1], o0[h + 2], o0[h + 3]};
        *(float4*)&f0t[(size_t)c * NPAD + pos0 + h] = v0;
#pragma unroll
        for (int z = 0; z < 3; ++z) {
            float4 v = {o1[h][z], o1[h + 1][z], o1[h + 2][z], o1[h + 3][z]};
            *(float4*)&f1t[(size_t)(c * 3 + z) * NPAD + pos0 + h] = v;
        }
    }
}

// ---------------- gate: gate[pos,k] = bias + sum_c scal[pos,c]*gk[s,c,k] ----------------
#define SCSTR 132
__global__ __launch_bounds__(256) void k_gate(
    const float* __restrict__ f0t, const int* __restrict__ blk_sp,
    const float* __restrict__ gk, const float* __restrict__ gb,
    float* __restrict__ gate) {
    int b = blockIdx.x;                 // 64-position tile
    int s = blk_sp[b >> 4];             // 16 tiles per 1024-seg
    if (s < 0) return;
    int p0 = b * 64;
    __shared__ float scal[64 * SCSTR];  // [pl][c]
    for (int i = threadIdx.x; i < 8192; i += 256) {
        int c = i >> 6, pl = i & 63;    // 64 consecutive pos per c -> coalesced
        scal[pl * SCSTR + c] = f0t[(size_t)c * NPAD + p0 + pl];
    }
    __syncthreads();
    int k = threadIdx.x;
    float bias = gb[s * 256 + k];
    float acc[64];
#pragma unroll
    for (int pl = 0; pl < 64; ++pl) acc[pl] = bias;
    const float* w = gk + (size_t)s * CC * 256 + k;
#pragma unroll 1
    for (int cb = 0; cb < 128; cb += 4) {
        float w0 = w[(cb + 0) * 256], w1 = w[(cb + 1) * 256];
        float w2 = w[(cb + 2) * 256], w3 = w[(cb + 3) * 256];
#pragma unroll
        for (int pl = 0; pl < 64; ++pl) {
            float4 f = *(const float4*)&scal[pl * SCSTR + cb];
            acc[pl] += f.x * w0 + f.y * w1 + f.z * w2 + f.w * w3;
        }
    }
#pragma unroll
    for (int pl = 0; pl < 64; ++pl)
        gate[(size_t)(p0 + pl) * 256 + k] = acc[pl];
}

// ---------------- gated equivariant linear + output scatter ----------------
#define FGSTR 516
__global__ __launch_bounds__(512) void k_linear(
    const float* __restrict__ f0t, const float* __restrict__ f1t,
    const float* __restrict__ gate, const int* __restrict__ order,
    const int* __restrict__ blk_sp, const float* __restrict__ lin0,
    const float* __restrict__ lin1, float* __restrict__ out) {
    int b = blockIdx.x;
    int s = blk_sp[b >> 6];             // 64 tiles (16 pos) per 1024-seg
    if (s < 0) return;
    int p0 = b * 16;
    __shared__ float gl[16 * 256];
    __shared__ float fg[16 * FGSTR];    // [pl][part*128+c]
    __shared__ int ord[16];
    int t = threadIdx.x;
    if (t < 16) ord[t] = order[p0 + t];
    for (int i = t; i < 4096; i += 512) gl[i] = gate[(size_t)p0 * 256 + i];
    __syncthreads();
    for (int i = t; i < 8192; i += 512) {
        int cp = i >> 4, pl = i & 15;   // 16 consecutive pos -> 64B segments
        int part = cp >> 7, c = cp & 127;
        float v;
        if (part == 0)
            v = f0t[(size_t)c * NPAD + p0 + pl] * gl[pl * 256 + c];
        else
            v = f1t[(size_t)(c * 3 + part - 1) * NPAD + p0 + pl] * gl[pl * 256 + 128 + c];
        fg[pl * FGSTR + part * 128 + c] = v;
    }
    __syncthreads();
    int k = t & 127, part = t >> 7;     // wave-uniform part
    const float* lin = (part == 0) ? lin0 : lin1;
    float acc[16];
#pragma unroll
    for (int pl = 0; pl < 16; ++pl) acc[pl] = 0.f;
#pragma unroll 1
    for (int cb = 0; cb < 128; cb += 4) {
        float w0 = lin[(cb + 0) * CC + k], w1 = lin[(cb + 1) * CC + k];
        float w2 = lin[(cb + 2) * CC + k], w3 = lin[(cb + 3) * CC + k];
#pragma unroll
        for (int pl = 0; pl < 16; ++pl) {
            float4 f = *(const float4*)&fg[pl * FGSTR + part * 128 + cb];
            acc[pl] += f.x * w0 + f.y * w1 + f.z * w2 + f.w * w3;
        }
    }
    const float inv = 0.08838834764831845f;   // 1/sqrt(128)
    int kk = (part == 0) ? k : (128 + k * 3 + (part - 1));
#pragma unroll
    for (int pl = 0; pl < 16; ++pl) {
        int n = ord[pl];
        if (n >= 0) out[(size_t)n * 512 + kk] = acc[pl] * inv;
    }
}

// ---------------------------------------------------------------------------
extern "C" void kernel_launch(void* const* d_in, const int* in_sizes, int n_in,
                              void* d_out, int out_size, void* d_ws, size_t ws_size,
                              hipStream_t stream) {
    const float* nf    = (const float*)d_in[0];
    const int*   sp    = (const int*)  d_in[1];
    const float* u1_0e = (const float*)d_in[2];
    const float* u2_0e = (const float*)d_in[3];
    const float* u3_0e = (const float*)d_in[4];
    const float* u1_1o = (const float*)d_in[5];
    const float* u2_1o = (const float*)d_in[6];
    const float* u3_1o = (const float*)d_in[7];
    const float* w1_0e = (const float*)d_in[8];
    const float* w2_0e = (const float*)d_in[9];
    const float* w3_0e = (const float*)d_in[10];
    const float* w1_1o = (const float*)d_in[11];
    const float* w2_1o = (const float*)d_in[12];
    const float* w3_1o = (const float*)d_in[13];
    const float* gk    = (const float*)d_in[14];
    const float* gb    = (const float*)d_in[15];
    const float* lin0  = (const float*)d_in[16];
    const float* lin1  = (const float*)d_in[17];

    float* ws   = (float*)d_ws;
    float* uw   = ws + OFF_UW;
    float* f0t  = ws + OFF_F0;
    float* f1t  = ws + OFF_F1;
    float* gate = ws + OFF_GATE;
    int* order  = (int*)(ws + OFF_ORD);
    int* meta   = (int*)(ws + OFF_META);
    int* counts = meta;          // 10 (16 reserved)
    int* cursor = meta + 16;     // 10
    int* blk_sp = meta + 32;     // 20

    hipMemsetAsync(counts, 0, 16 * sizeof(int), stream);
    hipMemsetAsync(order, 0xFF, NPAD * sizeof(int), stream);

    k_hist<<<40, 256, 0, stream>>>(sp, counts);
    k_plan<<<1, 64, 0, stream>>>(counts, cursor, blk_sp);
    k_scatter<<<40, 256, 0, stream>>>(sp, cursor, order);
    k_prep<<<CC * SS, 256, 0, stream>>>(u1_0e, u2_0e, u3_0e, u1_1o, u2_1o, u3_1o,
                                        w1_0e, w2_0e, w3_0e, w1_1o, w2_1o, w3_1o, uw);
    dim3 gm(MAXBLK, CC);
    k_contract<<<gm, 128, 0, stream>>>(nf, order, blk_sp, uw, f0t, f1t);
    k_gate<<<NPAD / 64, 256, 0, stream>>>(f0t, blk_sp, gk, gb, gate);
    k_linear<<<NPAD / 16, 512, 0, stream>>>(f0t, f1t, gate, order, blk_sp, lin0, lin1,
                                            (float*)d_out);
}

// Round 3
// 370.711 us; speedup vs baseline: 1.7765x; 1.7765x over previous
//
#include <hip/hip_runtime.h>

// ---------------------------------------------------------------------------
// EquivariantProductBasisBlock (MACE symmetric contraction + gate + linear)
// N=10000 nodes, C=128 channels, D=9 (0e+1o+2e), S=10 species.
// R3: k_contract = MM=4/256thr (no spill), j fully unrolled (register x),
// LDS = rec only (15.9 KB), select-chain for dynamic x[i].
// ---------------------------------------------------------------------------

#define NN 10000
#define CC 128
#define SS 10
#define NPB 1024                 // nodes per contraction segment
#define MAXBLK 20                // >= floor(N/NPB)+S = 9+10
#define NPAD (MAXBLK*NPB)        // 20480 padded positions
#define MM 4                     // nodes per thread in k_contract

// per-(c,s) record layout (floats):
//  [0,2916)   : 1o  [z][i][j][12] ; k=0..8 -> U3w_1o, [9]=U2w_1o, [10..11]=0
//  [2916,2944): U1w_1o [z][i] (27) + pad
//  [2944,3916): 0e  [i][j][12]   ; k=0..8 -> U3w_0e, [9]=U2w_0e
//  [3916,3928): U1w_0e [i] (9) + pad
#define U1_1O 2916
#define R0E   2944
#define U1_0E 3916
#define REC   3928

// ws layout (floats)
#define OFF_UW   0                         // CC*SS*REC = 5,027,840
#define OFF_F0   5027840                   // CC*NPAD   = 2,621,440
#define OFF_F1   7649280                   // 3*CC*NPAD = 7,864,320
#define OFF_GATE 15513600                  // NPAD*256  = 5,242,880
#define OFF_ORD  20756480                  // NPAD ints
#define OFF_META (OFF_ORD + NPAD)          // 64 ints
// total = 20,777,024 floats = 83.1 MB

// ---------------- species bucketing ----------------
__global__ void k_hist(const int* __restrict__ sp, int* __restrict__ counts) {
    int n = blockIdx.x * 256 + threadIdx.x;
    if (n < NN) atomicAdd(&counts[sp[n]], 1);
}

__global__ void k_plan(const int* __restrict__ counts, int* __restrict__ cursor,
                       int* __restrict__ blk_sp) {
    if (threadIdx.x != 0) return;
    int pos = 0, b = 0;
    for (int s = 0; s < SS; ++s) {
        cursor[s] = pos;
        int nb = (counts[s] + NPB - 1) / NPB;
        for (int i = 0; i < nb; ++i) blk_sp[b++] = s;
        pos += nb * NPB;
    }
    for (; b < MAXBLK; ++b) blk_sp[b] = -1;
}

__global__ void k_scatter(const int* __restrict__ sp, int* __restrict__ cursor,
                          int* __restrict__ order) {
    int n = blockIdx.x * 256 + threadIdx.x;
    if (n < NN) {
        int p = atomicAdd(&cursor[sp[n]], 1);
        order[p] = n;
    }
}

// ---------------- precompute U*w records ----------------
__global__ __launch_bounds__(256) void k_prep(
    const float* __restrict__ u1_0e, const float* __restrict__ u2_0e, const float* __restrict__ u3_0e,
    const float* __restrict__ u1_1o, const float* __restrict__ u2_1o, const float* __restrict__ u3_1o,
    const float* __restrict__ w1_0e, const float* __restrict__ w2_0e, const float* __restrict__ w3_0e,
    const float* __restrict__ w1_1o, const float* __restrict__ w2_1o, const float* __restrict__ w3_1o,
    float* __restrict__ uw) {
    int b = blockIdx.x;            // b = c*SS + s
    int c = b / SS, s = b % SS;
    float* rec = uw + (size_t)b * REC;
    for (int idx = threadIdx.x; idx < REC; idx += 256) {
        float v = 0.f;
        if (idx < 2916) {
            int q = idx / 12, k = idx % 12;        // q = (z*9+i)*9+j
            if (k < 9) {
                const float* u = u3_1o + (q * 9 + k) * 30;
                const float* w = w3_1o + s * 30 * CC + c;
                float a = 0.f;
                for (int p = 0; p < 30; ++p) a += u[p] * w[p * CC];
                v = a;
            } else if (k == 9) {
                const float* u = u2_1o + q * 4;
                const float* w = w2_1o + s * 4 * CC + c;
                float a = 0.f;
                for (int p = 0; p < 4; ++p) a += u[p] * w[p * CC];
                v = a;
            }
        } else if (idx < R0E) {
            int e = idx - U1_1O;                   // [z][i]
            if (e < 27) v = u1_1o[e] * w1_1o[s * CC + c];
        } else if (idx < U1_0E) {
            int e = idx - R0E;
            int q = e / 12, k = e % 12;            // q = i*9+j
            if (k < 9) {
                const float* u = u3_0e + (q * 9 + k) * 23;
                const float* w = w3_0e + s * 23 * CC + c;
                float a = 0.f;
                for (int p = 0; p < 23; ++p) a += u[p] * w[p * CC];
                v = a;
            } else if (k == 9) {
                const float* u = u2_0e + q * 4;
                const float* w = w2_0e + s * 4 * CC + c;
                float a = 0.f;
                for (int p = 0; p < 4; ++p) a += u[p] * w[p * CC];
                v = a;
            }
        } else {
            int e = idx - U1_0E;
            if (e < 9) v = u1_0e[e] * w1_0e[s * CC + c];
        }
        rec[idx] = v;
    }
}

// ---------------- symmetric contraction ----------------
// 256 threads x MM=4 nodes = 1024 nodes per block; j fully unrolled so x[m][j]
// is a static register; only x[m][i] needs a select chain (i dynamic).
__global__ __launch_bounds__(256, 2) void k_contract(
    const float* __restrict__ nf, const int* __restrict__ order,
    const int* __restrict__ blk_sp, const float* __restrict__ uw,
    float* __restrict__ f0t, float* __restrict__ f1t) {
    int b = blockIdx.x, c = blockIdx.y;
    int s = blk_sp[b];
    if (s < 0) return;                 // block-uniform exit
    __shared__ float rec[REC];

    int tid = threadIdx.x;
    int pos0 = b * NPB + tid * MM;

    // stage the (c,s) record (issue early; barrier below)
    const float* src = uw + (size_t)(c * SS + s) * REC;
    for (int i = tid * 4; i < REC; i += 1024)
        *(float4*)&rec[i] = *(const float4*)&src[i];

    // per-thread 4 nodes (segment is species-uniform)
    float x[MM][9];
#pragma unroll
    for (int m = 0; m < MM; ++m) {
        int n = order[pos0 + m];
        if (n >= 0) {
            const float* r = nf + (size_t)n * 1152;
            x[m][0] = r[c];
#pragma unroll
            for (int j = 0; j < 3; ++j) x[m][1 + j] = r[128 + c * 3 + j];
#pragma unroll
            for (int j = 0; j < 5; ++j) x[m][4 + j] = r[512 + c * 5 + j];
        } else {
#pragma unroll
            for (int k = 0; k < 9; ++k) x[m][k] = 0.f;
        }
    }

    __syncthreads();

    float o0[MM];
    float o1[MM][3];
#pragma unroll
    for (int m = 0; m < MM; ++m) {
        o0[m] = 0.f;
        o1[m][0] = 0.f; o1[m][1] = 0.f; o1[m][2] = 0.f;
    }

#pragma unroll 1
    for (int i = 0; i < 9; ++i) {
        // x[m][i] with dynamic i: select chain (cheap vs ~1440 FMAs/iter)
        float xi[MM];
#pragma unroll
        for (int m = 0; m < MM; ++m) {
            float v = x[m][0];
#pragma unroll
            for (int im = 1; im < 9; ++im) v = (i == im) ? x[m][im] : v;
            xi[m] = v;
        }

        // ---- 1o (z = 0..2) ----
#pragma unroll
        for (int z = 0; z < 3; ++z) {
            float B[MM];
#pragma unroll
            for (int m = 0; m < MM; ++m) B[m] = 0.f;
#pragma unroll
            for (int j = 0; j < 9; ++j) {
                const float* row = &rec[z * 972 + i * 108 + j * 12];
                float4 a  = *(const float4*)row;
                float4 bq = *(const float4*)(row + 4);
                float4 cq = *(const float4*)(row + 8);
#pragma unroll
                for (int m = 0; m < MM; ++m) {
                    float t = cq.y;                       // U2w
                    t += a.x * x[m][0]; t += a.y * x[m][1];
                    t += a.z * x[m][2]; t += a.w * x[m][3];
                    t += bq.x * x[m][4]; t += bq.y * x[m][5];
                    t += bq.z * x[m][6]; t += bq.w * x[m][7];
                    t += cq.x * x[m][8];
                    B[m] += t * x[m][j];                  // static j!
                }
            }
            float u1 = rec[U1_1O + z * 9 + i];
#pragma unroll
            for (int m = 0; m < MM; ++m) o1[m][z] += (u1 + B[m]) * xi[m];
        }

        // ---- 0e ----
        {
            float B[MM];
#pragma unroll
            for (int m = 0; m < MM; ++m) B[m] = 0.f;
#pragma unroll
            for (int j = 0; j < 9; ++j) {
                const float* row = &rec[R0E + i * 108 + j * 12];
                float4 a  = *(const float4*)row;
                float4 bq = *(const float4*)(row + 4);
                float4 cq = *(const float4*)(row + 8);
#pragma unroll
                for (int m = 0; m < MM; ++m) {
                    float t = cq.y;
                    t += a.x * x[m][0]; t += a.y * x[m][1];
                    t += a.z * x[m][2]; t += a.w * x[m][3];
                    t += bq.x * x[m][4]; t += bq.y * x[m][5];
                    t += bq.z * x[m][6]; t += bq.w * x[m][7];
                    t += cq.x * x[m][8];
                    B[m] += t * x[m][j];
                }
            }
            float u1 = rec[U1_0E + i];
#pragma unroll
            for (int m = 0; m < MM; ++m) o0[m] += (u1 + B[m]) * xi[m];
        }
    }

    // coalesced stores in sorted-position space (4 consecutive floats/thread)
    float4 v0 = {o0[0], o0[1], o0[2], o0[3]};
    *(float4*)&f0t[(size_t)c * NPAD + pos0] = v0;
#pragma unroll
    for (int z = 0; z < 3; ++z) {
        float4 v = {o1[0][z], o1[1][z], o1[2][z], o1[3][z]};
        *(float4*)&f1t[(size_t)(c * 3 + z) * NPAD + pos0] = v;
    }
}

// ---------------- gate: gate[pos,k] = bias + sum_c scal[pos,c]*gk[s,c,k] ----------------
#define SCSTR 132
__global__ __launch_bounds__(256) void k_gate(
    const float* __restrict__ f0t, const int* __restrict__ blk_sp,
    const float* __restrict__ gk, const float* __restrict__ gb,
    float* __restrict__ gate) {
    int b = blockIdx.x;                 // 64-position tile
    int s = blk_sp[b >> 4];             // 16 tiles per 1024-seg
    if (s < 0) return;
    int p0 = b * 64;
    __shared__ float scal[64 * SCSTR];  // [pl][c]
    for (int i = threadIdx.x; i < 8192; i += 256) {
        int c = i >> 6, pl = i & 63;    // 64 consecutive pos per c -> coalesced
        scal[pl * SCSTR + c] = f0t[(size_t)c * NPAD + p0 + pl];
    }
    __syncthreads();
    int k = threadIdx.x;
    float bias = gb[s * 256 + k];
    float acc[64];
#pragma unroll
    for (int pl = 0; pl < 64; ++pl) acc[pl] = bias;
    const float* w = gk + (size_t)s * CC * 256 + k;
#pragma unroll 1
    for (int cb = 0; cb < 128; cb += 4) {
        float w0 = w[(cb + 0) * 256], w1 = w[(cb + 1) * 256];
        float w2 = w[(cb + 2) * 256], w3 = w[(cb + 3) * 256];
#pragma unroll
        for (int pl = 0; pl < 64; ++pl) {
            float4 f = *(const float4*)&scal[pl * SCSTR + cb];
            acc[pl] += f.x * w0 + f.y * w1 + f.z * w2 + f.w * w3;
        }
    }
#pragma unroll
    for (int pl = 0; pl < 64; ++pl)
        gate[(size_t)(p0 + pl) * 256 + k] = acc[pl];
}

// ---------------- gated equivariant linear + output scatter ----------------
#define FGSTR 516
__global__ __launch_bounds__(512) void k_linear(
    const float* __restrict__ f0t, const float* __restrict__ f1t,
    const float* __restrict__ gate, const int* __restrict__ order,
    const int* __restrict__ blk_sp, const float* __restrict__ lin0,
    const float* __restrict__ lin1, float* __restrict__ out) {
    int b = blockIdx.x;
    int s = blk_sp[b >> 6];             // 64 tiles (16 pos) per 1024-seg
    if (s < 0) return;
    int p0 = b * 16;
    __shared__ float gl[16 * 256];
    __shared__ float fg[16 * FGSTR];    // [pl][part*128+c]
    __shared__ int ord[16];
    int t = threadIdx.x;
    if (t < 16) ord[t] = order[p0 + t];
    for (int i = t; i < 4096; i += 512) gl[i] = gate[(size_t)p0 * 256 + i];
    __syncthreads();
    for (int i = t; i < 8192; i += 512) {
        int cp = i >> 4, pl = i & 15;   // 16 consecutive pos -> 64B segments
        int part = cp >> 7, c = cp & 127;
        float v;
        if (part == 0)
            v = f0t[(size_t)c * NPAD + p0 + pl] * gl[pl * 256 + c];
        else
            v = f1t[(size_t)(c * 3 + part - 1) * NPAD + p0 + pl] * gl[pl * 256 + 128 + c];
        fg[pl * FGSTR + part * 128 + c] = v;
    }
    __syncthreads();
    int k = t & 127, part = t >> 7;     // wave-uniform part
    const float* lin = (part == 0) ? lin0 : lin1;
    float acc[16];
#pragma unroll
    for (int pl = 0; pl < 16; ++pl) acc[pl] = 0.f;
#pragma unroll 1
    for (int cb = 0; cb < 128; cb += 4) {
        float w0 = lin[(cb + 0) * CC + k], w1 = lin[(cb + 1) * CC + k];
        float w2 = lin[(cb + 2) * CC + k], w3 = lin[(cb + 3) * CC + k];
#pragma unroll
        for (int pl = 0; pl < 16; ++pl) {
            float4 f = *(const float4*)&fg[pl * FGSTR + part * 128 + cb];
            acc[pl] += f.x * w0 + f.y * w1 + f.z * w2 + f.w * w3;
        }
    }
    const float inv = 0.08838834764831845f;   // 1/sqrt(128)
    int kk = (part == 0) ? k : (128 + k * 3 + (part - 1));
#pragma unroll
    for (int pl = 0; pl < 16; ++pl) {
        int n = ord[pl];
        if (n >= 0) out[(size_t)n * 512 + kk] = acc[pl] * inv;
    }
}

// ---------------------------------------------------------------------------
extern "C" void kernel_launch(void* const* d_in, const int* in_sizes, int n_in,
                              void* d_out, int out_size, void* d_ws, size_t ws_size,
                              hipStream_t stream) {
    const float* nf    = (const float*)d_in[0];
    const int*   sp    = (const int*)  d_in[1];
    const float* u1_0e = (const float*)d_in[2];
    const float* u2_0e = (const float*)d_in[3];
    const float* u3_0e = (const float*)d_in[4];
    const float* u1_1o = (const float*)d_in[5];
    const float* u2_1o = (const float*)d_in[6];
    const float* u3_1o = (const float*)d_in[7];
    const float* w1_0e = (const float*)d_in[8];
    const float* w2_0e = (const float*)d_in[9];
    const float* w3_0e = (const float*)d_in[10];
    const float* w1_1o = (const float*)d_in[11];
    const float* w2_1o = (const float*)d_in[12];
    const float* w3_1o = (const float*)d_in[13];
    const float* gk    = (const float*)d_in[14];
    const float* gb    = (const float*)d_in[15];
    const float* lin0  = (const float*)d_in[16];
    const float* lin1  = (const float*)d_in[17];

    float* ws   = (float*)d_ws;
    float* uw   = ws + OFF_UW;
    float* f0t  = ws + OFF_F0;
    float* f1t  = ws + OFF_F1;
    float* gate = ws + OFF_GATE;
    int* order  = (int*)(ws + OFF_ORD);
    int* meta   = (int*)(ws + OFF_META);
    int* counts = meta;          // 10 (16 reserved)
    int* cursor = meta + 16;     // 10
    int* blk_sp = meta + 32;     // 20

    hipMemsetAsync(counts, 0, 16 * sizeof(int), stream);
    hipMemsetAsync(order, 0xFF, NPAD * sizeof(int), stream);

    k_hist<<<40, 256, 0, stream>>>(sp, counts);
    k_plan<<<1, 64, 0, stream>>>(counts, cursor, blk_sp);
    k_scatter<<<40, 256, 0, stream>>>(sp, cursor, order);
    k_prep<<<CC * SS, 256, 0, stream>>>(u1_0e, u2_0e, u3_0e, u1_1o, u2_1o, u3_1o,
                                        w1_0e, w2_0e, w3_0e, w1_1o, w2_1o, w3_1o, uw);
    dim3 gm(MAXBLK, CC);
    k_contract<<<gm, 256, 0, stream>>>(nf, order, blk_sp, uw, f0t, f1t);
    k_gate<<<NPAD / 64, 256, 0, stream>>>(f0t, blk_sp, gk, gb, gate);
    k_linear<<<NPAD / 16, 512, 0, stream>>>(f0t, f1t, gate, order, blk_sp, lin0, lin1,
                                            (float*)d_out);
}

// Round 4
// 354.899 us; speedup vs baseline: 1.8556x; 1.0446x over previous
//
#include <hip/hip_runtime.h>

// ---------------------------------------------------------------------------
// EquivariantProductBasisBlock (MACE symmetric contraction + gate + linear)
// N=10000, C=128, D=9, S=10.
// R4: contraction as bf16 MFMA. Per (c,s): B[40r x 54k] = M . y(x),
//   y = [45 sym pairs x_a*x_b | 9 linear x_j | 10 pad], rows: 36 zi + 4 u1.
//   6x mfma_f32_16x16x32_bf16 per (16 nodes, channel). fp32 epilogue.
// ---------------------------------------------------------------------------

#define NN 10000
#define CC 128
#define SS 10
#define NPB 1024
#define MAXBLK 20
#define NPAD (MAXBLK*NPB)        // 20480

typedef unsigned short u16;
typedef __attribute__((ext_vector_type(8))) short bf16x8;
typedef __attribute__((ext_vector_type(4))) float f32x4;

// y-index pair tables: k<45 sym pairs (a<=b); 45..53 linear (j,one); 54+ zero
// xx[9]=1.0, xx[10]=0.0
__device__ constexpr int PA[64] = {
    0,0,0,0,0,0,0,0,0,
    1,1,1,1,1,1,1,1,
    2,2,2,2,2,2,2,
    3,3,3,3,3,3,
    4,4,4,4,4,
    5,5,5,5,
    6,6,6,
    7,7,
    8,
    0,1,2,3,4,5,6,7,8,
    10,10,10,10,10,10,10,10,10,10};
__device__ constexpr int PB[64] = {
    0,1,2,3,4,5,6,7,8,
    1,2,3,4,5,6,7,8,
    2,3,4,5,6,7,8,
    3,4,5,6,7,8,
    4,5,6,7,8,
    5,6,7,8,
    6,7,8,
    7,8,
    8,
    9,9,9,9,9,9,9,9,9,
    10,10,10,10,10,10,10,10,10,10};

// A-frag layout per (c,s): [blk3][kh2][lane64][e8] bf16 = 3072 u16 = 6KB.
//   element = M[row = blk*16 + (lane&15)][k = kh*32 + (lane>>4)*8 + e]
#define AFRAG_U16 3072

// ws layout (floats)
#define OFF_AF   0                          // 1280*3072 u16 = 1,966,080 f
#define OFF_F0   1966080                    // CC*NPAD   = 2,621,440
#define OFF_F1   4587520                    // 3*CC*NPAD = 7,864,320
#define OFF_GATE 12451840                   // NPAD*256  = 5,242,880
#define OFF_ORD  17694720                   // NPAD ints
#define OFF_META (OFF_ORD + NPAD)           // 64 ints
// total ~ 17.72M floats = 70.9 MB

__device__ __forceinline__ u16 bf16rne(float f) {
    unsigned u = __float_as_uint(f);
    u += 0x7fffu + ((u >> 16) & 1u);
    return (u16)(u >> 16);
}

// ---------------- species bucketing ----------------
__global__ void k_hist(const int* __restrict__ sp, int* __restrict__ counts) {
    int n = blockIdx.x * 256 + threadIdx.x;
    if (n < NN) atomicAdd(&counts[sp[n]], 1);
}

__global__ void k_plan(const int* __restrict__ counts, int* __restrict__ cursor,
                       int* __restrict__ blk_sp) {
    if (threadIdx.x != 0) return;
    int pos = 0, b = 0;
    for (int s = 0; s < SS; ++s) {
        cursor[s] = pos;
        int nb = (counts[s] + NPB - 1) / NPB;
        for (int i = 0; i < nb; ++i) blk_sp[b++] = s;
        pos += nb * NPB;
    }
    for (; b < MAXBLK; ++b) blk_sp[b] = -1;
}

__global__ void k_scatter(const int* __restrict__ sp, int* __restrict__ cursor,
                          int* __restrict__ order) {
    int n = blockIdx.x * 256 + threadIdx.x;
    if (n < NN) {
        int p = atomicAdd(&cursor[sp[n]], 1);
        order[p] = n;
    }
}

// ---------------- prep: build M in A-fragment layout (bf16) ----------------
// grid (40 rows, 10 s), 128 threads = c. Rows 0..35: sec=row/9 (0..2 = 1o z,
// 3 = 0e), i=row%9. Rows 36..39: u1 rows (z=row-36, 3=0e).
__global__ __launch_bounds__(128) void k_prep2(
    const float* __restrict__ u1_0e, const float* __restrict__ u2_0e, const float* __restrict__ u3_0e,
    const float* __restrict__ u1_1o, const float* __restrict__ u2_1o, const float* __restrict__ u3_1o,
    const float* __restrict__ w1_0e, const float* __restrict__ w2_0e, const float* __restrict__ w3_0e,
    const float* __restrict__ w1_1o, const float* __restrict__ w2_1o, const float* __restrict__ w3_1o,
    u16* __restrict__ af) {
    int row = blockIdx.x, s = blockIdx.y, c = threadIdx.x;
    u16* base = af + (size_t)(c * SS + s) * AFRAG_U16;
    int blk = row >> 4, r16 = row & 15;
    auto emit = [&](int k, float v) {
        int kh = k >> 5, kr = k & 31, g = kr >> 3, e = k & 7;
        base[(((blk * 2 + kh) * 64 + g * 16 + r16) << 3) + e] = bf16rne(v);
    };
    if (row < 36) {
        int sec = row / 9, i = row % 9;
        if (sec < 3) {
            float w[30];
#pragma unroll 1
            for (int p = 0; p < 30; ++p) w[p] = w3_1o[(s * 30 + p) * CC + c];
            int k = 0;
#pragma unroll 1
            for (int a = 0; a < 9; ++a)
#pragma unroll 1
                for (int b = a; b < 9; ++b) {
                    const float* ua = u3_1o + (size_t)((((sec * 9 + i) * 9 + a) * 9 + b)) * 30;
                    const float* ub = u3_1o + (size_t)((((sec * 9 + i) * 9 + b) * 9 + a)) * 30;
                    float acc = 0.f;
                    if (a == b) { for (int p = 0; p < 30; ++p) acc += ua[p] * w[p]; }
                    else        { for (int p = 0; p < 30; ++p) acc += (ua[p] + ub[p]) * w[p]; }
                    emit(k++, acc);
                }
            float w2[4];
#pragma unroll
            for (int p = 0; p < 4; ++p) w2[p] = w2_1o[(s * 4 + p) * CC + c];
#pragma unroll 1
            for (int j = 0; j < 9; ++j) {
                const float* u = u2_1o + (size_t)(((sec * 9 + i) * 9 + j)) * 4;
                float acc = 0.f;
                for (int p = 0; p < 4; ++p) acc += u[p] * w2[p];
                emit(45 + j, acc);
            }
        } else {
            int i0 = i;
            float w[23];
#pragma unroll 1
            for (int p = 0; p < 23; ++p) w[p] = w3_0e[(s * 23 + p) * CC + c];
            int k = 0;
#pragma unroll 1
            for (int a = 0; a < 9; ++a)
#pragma unroll 1
                for (int b = a; b < 9; ++b) {
                    const float* ua = u3_0e + (size_t)(((i0 * 9 + a) * 9 + b)) * 23;
                    const float* ub = u3_0e + (size_t)(((i0 * 9 + b) * 9 + a)) * 23;
                    float acc = 0.f;
                    if (a == b) { for (int p = 0; p < 23; ++p) acc += ua[p] * w[p]; }
                    else        { for (int p = 0; p < 23; ++p) acc += (ua[p] + ub[p]) * w[p]; }
                    emit(k++, acc);
                }
            float w2[4];
#pragma unroll
            for (int p = 0; p < 4; ++p) w2[p] = w2_0e[(s * 4 + p) * CC + c];
#pragma unroll 1
            for (int j = 0; j < 9; ++j) {
                const float* u = u2_0e + (size_t)((i0 * 9 + j)) * 4;
                float acc = 0.f;
                for (int p = 0; p < 4; ++p) acc += u[p] * w2[p];
                emit(45 + j, acc);
            }
        }
    } else {
        int z = row - 36;
        if (z < 3) {
            float wv = w1_1o[s * CC + c];
#pragma unroll 1
            for (int i = 0; i < 9; ++i) emit(45 + i, u1_1o[z * 9 + i] * wv);
        } else {
            float wv = w1_0e[s * CC + c];
#pragma unroll 1
            for (int i = 0; i < 9; ++i) emit(45 + i, u1_0e[i] * wv);
        }
    }
}

// ---------------- symmetric contraction via MFMA ----------------
// block = 64 nodes (one tile) x 1 channel; 4 waves, each owns 16 nodes.
__global__ __launch_bounds__(256) void k_contract(
    const float* __restrict__ nf, const int* __restrict__ order,
    const int* __restrict__ blk_sp, const u16* __restrict__ af_g,
    float* __restrict__ f0t, float* __restrict__ f1t) {
    int tile = blockIdx.x;               // 0..319
    int c = blockIdx.y;
    int s = blk_sp[tile >> 4];
    if (s < 0) return;                   // block-uniform exit

    __shared__ __align__(16) u16 afl[AFRAG_U16];
    __shared__ __align__(16) float xl[64 * 12];
    __shared__ float Bl[4 * 816];        // per-wave [48 rows][stride 17]

    int tid = threadIdx.x;
    int pos_base = tile * 64;

    // stage A-fragments (6 KB)
    {
        const uint4* ag = (const uint4*)(af_g + (size_t)(c * SS + s) * AFRAG_U16);
        uint4* al = (uint4*)afl;
        al[tid & 255] = ag[tid & 255];
        if (tid < 128) al[256 + tid] = ag[256 + tid];
    }
    // stage x: wave w loads its element-set for all 64 nodes
    {
        int n_l = tid & 63, w = tid >> 6;
        int n = order[pos_base + n_l];
        const float* r = (n >= 0) ? (nf + (size_t)n * 1152) : nullptr;
        if (w == 0) {
            xl[n_l * 12 + 0] = r ? r[c] : 0.f;
            xl[n_l * 12 + 9] = 0.f; xl[n_l * 12 + 10] = 0.f; xl[n_l * 12 + 11] = 0.f;
        } else if (w == 1) {
#pragma unroll
            for (int j = 0; j < 3; ++j) xl[n_l * 12 + 1 + j] = r ? r[128 + c * 3 + j] : 0.f;
        } else if (w == 2) {
#pragma unroll
            for (int j = 0; j < 2; ++j) xl[n_l * 12 + 4 + j] = r ? r[512 + c * 5 + j] : 0.f;
        } else {
#pragma unroll
            for (int j = 2; j < 5; ++j) xl[n_l * 12 + 4 + j] = r ? r[512 + c * 5 + j] : 0.f;
        }
    }
    __syncthreads();

    int lane = tid & 63, wave = tid >> 6;
    int n16 = lane & 15, g = lane >> 4;
    int myn = wave * 16 + n16;

    float xx[11];
    {
        float4 t0 = *(float4*)&xl[myn * 12];
        float4 t1 = *(float4*)&xl[myn * 12 + 4];
        xx[0] = t0.x; xx[1] = t0.y; xx[2] = t0.z; xx[3] = t0.w;
        xx[4] = t1.x; xx[5] = t1.y; xx[6] = t1.z; xx[7] = t1.w;
        xx[8] = xl[myn * 12 + 8];
    }
    xx[9] = 1.f; xx[10] = 0.f;

    // build y fragments (bf16x8 per K-half), group-dependent pair tables
    bf16x8 yf0, yf1;
#pragma unroll
    for (int kh = 0; kh < 2; ++kh) {
        unsigned packed[4];
#pragma unroll
        for (int ep = 0; ep < 4; ++ep) {
            unsigned pk = 0;
#pragma unroll
            for (int h = 0; h < 2; ++h) {
                const int e = ep * 2 + h;
                const int kb = kh * 32 + e;
                float xa = xx[PA[kb]];
                xa = (g == 1) ? xx[PA[kb + 8]]  : xa;
                xa = (g == 2) ? xx[PA[kb + 16]] : xa;
                xa = (g == 3) ? xx[PA[kb + 24]] : xa;
                float xb = xx[PB[kb]];
                xb = (g == 1) ? xx[PB[kb + 8]]  : xb;
                xb = (g == 2) ? xx[PB[kb + 16]] : xb;
                xb = (g == 3) ? xx[PB[kb + 24]] : xb;
                pk |= ((unsigned)bf16rne(xa * xb)) << (16 * h);
            }
            packed[ep] = pk;
        }
        uint4 u = {packed[0], packed[1], packed[2], packed[3]};
        if (kh == 0) yf0 = __builtin_bit_cast(bf16x8, u);
        else         yf1 = __builtin_bit_cast(bf16x8, u);
    }

    // 6 MFMAs: acc[blk] over 2 K-halves
    f32x4 acc0 = {0.f, 0.f, 0.f, 0.f}, acc1 = acc0, acc2 = acc0;
    {
        const bf16x8* afv = (const bf16x8*)afl;
        acc0 = __builtin_amdgcn_mfma_f32_16x16x32_bf16(afv[0 * 64 + lane], yf0, acc0, 0, 0, 0);
        acc0 = __builtin_amdgcn_mfma_f32_16x16x32_bf16(afv[1 * 64 + lane], yf1, acc0, 0, 0, 0);
        acc1 = __builtin_amdgcn_mfma_f32_16x16x32_bf16(afv[2 * 64 + lane], yf0, acc1, 0, 0, 0);
        acc1 = __builtin_amdgcn_mfma_f32_16x16x32_bf16(afv[3 * 64 + lane], yf1, acc1, 0, 0, 0);
        acc2 = __builtin_amdgcn_mfma_f32_16x16x32_bf16(afv[4 * 64 + lane], yf0, acc2, 0, 0, 0);
        acc2 = __builtin_amdgcn_mfma_f32_16x16x32_bf16(afv[5 * 64 + lane], yf1, acc2, 0, 0, 0);
    }

    // scatter B to LDS: row = blk*16 + g*4 + r, col = n16
    float* bw = &Bl[wave * 816];
#pragma unroll
    for (int r = 0; r < 4; ++r) bw[(0 * 16 + g * 4 + r) * 17 + n16] = acc0[r];
#pragma unroll
    for (int r = 0; r < 4; ++r) bw[(1 * 16 + g * 4 + r) * 17 + n16] = acc1[r];
#pragma unroll
    for (int r = 0; r < 4; ++r) bw[(2 * 16 + g * 4 + r) * 17 + n16] = acc2[r];
    __syncthreads();

    // epilogue: lane handles (node=n16, section=g): val = sum_i B[g*9+i]*x_i + B[36+g]
    const float* br = &Bl[wave * 816];
    float val = br[(36 + g) * 17 + n16];
#pragma unroll
    for (int i = 0; i < 9; ++i) val += br[(g * 9 + i) * 17 + n16] * xx[i];

    int pos = pos_base + myn;
    if (g == 3) f0t[(size_t)c * NPAD + pos] = val;
    else        f1t[(size_t)(c * 3 + g) * NPAD + pos] = val;
}

// ---------------- gate: gate[pos,k] = bias + sum_c scal[pos,c]*gk[s,c,k] ----------------
#define SCSTR 132
__global__ __launch_bounds__(256) void k_gate(
    const float* __restrict__ f0t, const int* __restrict__ blk_sp,
    const float* __restrict__ gk, const float* __restrict__ gb,
    float* __restrict__ gate) {
    int b = blockIdx.x;                 // 64-position tile
    int s = blk_sp[b >> 4];
    if (s < 0) return;
    int p0 = b * 64;
    __shared__ float scal[64 * SCSTR];
    for (int i = threadIdx.x; i < 8192; i += 256) {
        int c = i >> 6, pl = i & 63;
        scal[pl * SCSTR + c] = f0t[(size_t)c * NPAD + p0 + pl];
    }
    __syncthreads();
    int k = threadIdx.x;
    float bias = gb[s * 256 + k];
    float acc[64];
#pragma unroll
    for (int pl = 0; pl < 64; ++pl) acc[pl] = bias;
    const float* w = gk + (size_t)s * CC * 256 + k;
#pragma unroll 1
    for (int cb = 0; cb < 128; cb += 4) {
        float w0 = w[(cb + 0) * 256], w1 = w[(cb + 1) * 256];
        float w2 = w[(cb + 2) * 256], w3 = w[(cb + 3) * 256];
#pragma unroll
        for (int pl = 0; pl < 64; ++pl) {
            float4 f = *(const float4*)&scal[pl * SCSTR + cb];
            acc[pl] += f.x * w0 + f.y * w1 + f.z * w2 + f.w * w3;
        }
    }
#pragma unroll
    for (int pl = 0; pl < 64; ++pl)
        gate[(size_t)(p0 + pl) * 256 + k] = acc[pl];
}

// ---------------- gated equivariant linear + output scatter ----------------
#define FGSTR 516
__global__ __launch_bounds__(512) void k_linear(
    const float* __restrict__ f0t, const float* __restrict__ f1t,
    const float* __restrict__ gate, const int* __restrict__ order,
    const int* __restrict__ blk_sp, const float* __restrict__ lin0,
    const float* __restrict__ lin1, float* __restrict__ out) {
    int b = blockIdx.x;
    int s = blk_sp[b >> 6];
    if (s < 0) return;
    int p0 = b * 16;
    __shared__ float gl[16 * 256];
    __shared__ float fg[16 * FGSTR];
    __shared__ int ord[16];
    int t = threadIdx.x;
    if (t < 16) ord[t] = order[p0 + t];
    for (int i = t; i < 4096; i += 512) gl[i] = gate[(size_t)p0 * 256 + i];
    __syncthreads();
    for (int i = t; i < 8192; i += 512) {
        int cp = i >> 4, pl = i & 15;
        int part = cp >> 7, c = cp & 127;
        float v;
        if (part == 0)
            v = f0t[(size_t)c * NPAD + p0 + pl] * gl[pl * 256 + c];
        else
            v = f1t[(size_t)(c * 3 + part - 1) * NPAD + p0 + pl] * gl[pl * 256 + 128 + c];
        fg[pl * FGSTR + part * 128 + c] = v;
    }
    __syncthreads();
    int k = t & 127, part = t >> 7;
    const float* lin = (part == 0) ? lin0 : lin1;
    float acc[16];
#pragma unroll
    for (int pl = 0; pl < 16; ++pl) acc[pl] = 0.f;
#pragma unroll 1
    for (int cb = 0; cb < 128; cb += 4) {
        float w0 = lin[(cb + 0) * CC + k], w1 = lin[(cb + 1) * CC + k];
        float w2 = lin[(cb + 2) * CC + k], w3 = lin[(cb + 3) * CC + k];
#pragma unroll
        for (int pl = 0; pl < 16; ++pl) {
            float4 f = *(const float4*)&fg[pl * FGSTR + part * 128 + cb];
            acc[pl] += f.x * w0 + f.y * w1 + f.z * w2 + f.w * w3;
        }
    }
    const float inv = 0.08838834764831845f;   // 1/sqrt(128)
    int kk = (part == 0) ? k : (128 + k * 3 + (part - 1));
#pragma unroll
    for (int pl = 0; pl < 16; ++pl) {
        int n = ord[pl];
        if (n >= 0) out[(size_t)n * 512 + kk] = acc[pl] * inv;
    }
}

// ---------------------------------------------------------------------------
extern "C" void kernel_launch(void* const* d_in, const int* in_sizes, int n_in,
                              void* d_out, int out_size, void* d_ws, size_t ws_size,
                              hipStream_t stream) {
    const float* nf    = (const float*)d_in[0];
    const int*   sp    = (const int*)  d_in[1];
    const float* u1_0e = (const float*)d_in[2];
    const float* u2_0e = (const float*)d_in[3];
    const float* u3_0e = (const float*)d_in[4];
    const float* u1_1o = (const float*)d_in[5];
    const float* u2_1o = (const float*)d_in[6];
    const float* u3_1o = (const float*)d_in[7];
    const float* w1_0e = (const float*)d_in[8];
    const float* w2_0e = (const float*)d_in[9];
    const float* w3_0e = (const float*)d_in[10];
    const float* w1_1o = (const float*)d_in[11];
    const float* w2_1o = (const float*)d_in[12];
    const float* w3_1o = (const float*)d_in[13];
    const float* gk    = (const float*)d_in[14];
    const float* gb    = (const float*)d_in[15];
    const float* lin0  = (const float*)d_in[16];
    const float* lin1  = (const float*)d_in[17];

    float* ws   = (float*)d_ws;
    u16*  af    = (u16*)(ws + OFF_AF);
    float* f0t  = ws + OFF_F0;
    float* f1t  = ws + OFF_F1;
    float* gate = ws + OFF_GATE;
    int* order  = (int*)(ws + OFF_ORD);
    int* meta   = (int*)(ws + OFF_META);
    int* counts = meta;
    int* cursor = meta + 16;
    int* blk_sp = meta + 32;

    hipMemsetAsync(counts, 0, 16 * sizeof(int), stream);
    hipMemsetAsync(order, 0xFF, NPAD * sizeof(int), stream);
    hipMemsetAsync(af, 0, (size_t)CC * SS * AFRAG_U16 * sizeof(u16), stream);

    k_hist<<<40, 256, 0, stream>>>(sp, counts);
    k_plan<<<1, 64, 0, stream>>>(counts, cursor, blk_sp);
    k_scatter<<<40, 256, 0, stream>>>(sp, cursor, order);
    dim3 gp(40, SS);
    k_prep2<<<gp, 128, 0, stream>>>(u1_0e, u2_0e, u3_0e, u1_1o, u2_1o, u3_1o,
                                    w1_0e, w2_0e, w3_0e, w1_1o, w2_1o, w3_1o, af);
    dim3 gm(NPAD / 64, CC);
    k_contract<<<gm, 256, 0, stream>>>(nf, order, blk_sp, af, f0t, f1t);
    k_gate<<<NPAD / 64, 256, 0, stream>>>(f0t, blk_sp, gk, gb, gate);
    k_linear<<<NPAD / 16, 512, 0, stream>>>(f0t, f1t, gate, order, blk_sp, lin0, lin1,
                                            (float*)d_out);
}

// Round 6
// 229.149 us; speedup vs baseline: 2.8739x; 1.5488x over previous
//
#include <hip/hip_runtime.h>

// ---------------------------------------------------------------------------
// EquivariantProductBasisBlock (MACE symmetric contraction + gate + linear)
// N=10000, C=128, D=9, S=10.
// R6 = R5 + fix: Bl scatter overflow (rows 40..47 of blk2 were written,
// overrunning the 16x43 per-wave region into the next wave's B rows).
// Only rows 32..39 are meaningful -> guard acc2 store with g<2.
// ---------------------------------------------------------------------------

#define NN 10000
#define CC 128
#define SS 10
#define NPB 1024
#define MAXBLK 20
#define NPAD (MAXBLK*NPB)        // 20480

typedef unsigned short u16;
typedef __attribute__((ext_vector_type(8))) short bf16x8;
typedef __attribute__((ext_vector_type(4))) float f32x4;

// sym-pair tables for y slots 0..44 (a<=b); slots 45..53 = linear x_j; 54+ = 0
__device__ constexpr int PA[45] = {
    0,0,0,0,0,0,0,0,0,
    1,1,1,1,1,1,1,1,
    2,2,2,2,2,2,2,
    3,3,3,3,3,3,
    4,4,4,4,4,
    5,5,5,5,
    6,6,6,
    7,7,
    8};
__device__ constexpr int PB[45] = {
    0,1,2,3,4,5,6,7,8,
    1,2,3,4,5,6,7,8,
    2,3,4,5,6,7,8,
    3,4,5,6,7,8,
    4,5,6,7,8,
    5,6,7,8,
    6,7,8,
    7,8,
    8};

// A-frag layout per (c,s): [blk3][kh2][lane64][e8] bf16 = 3072 u16 = 6KB.
//   element = M[row = blk*16 + (lane&15)][k = kh*32 + (lane>>4)*8 + e]
#define AFRAG_U16 3072

// ws layout (floats)
#define OFF_AF   0                          // 1280*3072 u16 = 1,966,080 f
#define OFF_F0   1966080                    // CC*NPAD   = 2,621,440
#define OFF_F1   4587520                    // 3*CC*NPAD = 7,864,320
#define OFF_GKF  12451840                   // 327,680 u16 = 163,840 f
#define OFF_LINF 12615680                   // 32,768 u16 = 16,384 f
#define OFF_ORD  12632064                   // NPAD ints
#define OFF_META (OFF_ORD + NPAD)           // 64 ints
// total = 12,652,608 floats = 50.6 MB

__device__ __forceinline__ u16 bf16rne(float f) {
    unsigned u = __float_as_uint(f);
    u += 0x7fffu + ((u >> 16) & 1u);
    return (u16)(u >> 16);
}
__device__ __forceinline__ float bf2f(u16 h) {
    return __uint_as_float(((unsigned)h) << 16);
}

// ---------------- species bucketing ----------------
__global__ void k_hist(const int* __restrict__ sp, int* __restrict__ counts) {
    int n = blockIdx.x * 256 + threadIdx.x;
    if (n < NN) atomicAdd(&counts[sp[n]], 1);
}

__global__ void k_plan(const int* __restrict__ counts, int* __restrict__ cursor,
                       int* __restrict__ blk_sp) {
    if (threadIdx.x != 0) return;
    int pos = 0, b = 0;
    for (int s = 0; s < SS; ++s) {
        cursor[s] = pos;
        int nb = (counts[s] + NPB - 1) / NPB;
        for (int i = 0; i < nb; ++i) blk_sp[b++] = s;
        pos += nb * NPB;
    }
    for (; b < MAXBLK; ++b) blk_sp[b] = -1;
}

__global__ void k_scatter(const int* __restrict__ sp, int* __restrict__ cursor,
                          int* __restrict__ order) {
    int n = blockIdx.x * 256 + threadIdx.x;
    if (n < NN) {
        int p = atomicAdd(&cursor[sp[n]], 1);
        order[p] = n;
    }
}

// ---------------- prep: build M in A-fragment layout (bf16) ----------------
__global__ __launch_bounds__(128) void k_prep2(
    const float* __restrict__ u1_0e, const float* __restrict__ u2_0e, const float* __restrict__ u3_0e,
    const float* __restrict__ u1_1o, const float* __restrict__ u2_1o, const float* __restrict__ u3_1o,
    const float* __restrict__ w1_0e, const float* __restrict__ w2_0e, const float* __restrict__ w3_0e,
    const float* __restrict__ w1_1o, const float* __restrict__ w2_1o, const float* __restrict__ w3_1o,
    u16* __restrict__ af) {
    int row = blockIdx.x, s = blockIdx.y, c = threadIdx.x;
    u16* base = af + (size_t)(c * SS + s) * AFRAG_U16;
    int blk = row >> 4, r16 = row & 15;
    auto emit = [&](int k, float v) {
        int kh = k >> 5, kr = k & 31, g = kr >> 3, e = k & 7;
        base[(((blk * 2 + kh) * 64 + g * 16 + r16) << 3) + e] = bf16rne(v);
    };
    if (row < 36) {
        int sec = row / 9, i = row % 9;
        if (sec < 3) {
            float w[30];
#pragma unroll 1
            for (int p = 0; p < 30; ++p) w[p] = w3_1o[(s * 30 + p) * CC + c];
            int k = 0;
#pragma unroll 1
            for (int a = 0; a < 9; ++a)
#pragma unroll 1
                for (int b = a; b < 9; ++b) {
                    const float* ua = u3_1o + (size_t)((((sec * 9 + i) * 9 + a) * 9 + b)) * 30;
                    const float* ub = u3_1o + (size_t)((((sec * 9 + i) * 9 + b) * 9 + a)) * 30;
                    float acc = 0.f;
                    if (a == b) { for (int p = 0; p < 30; ++p) acc += ua[p] * w[p]; }
                    else        { for (int p = 0; p < 30; ++p) acc += (ua[p] + ub[p]) * w[p]; }
                    emit(k++, acc);
                }
            float w2[4];
#pragma unroll
            for (int p = 0; p < 4; ++p) w2[p] = w2_1o[(s * 4 + p) * CC + c];
#pragma unroll 1
            for (int j = 0; j < 9; ++j) {
                const float* u = u2_1o + (size_t)(((sec * 9 + i) * 9 + j)) * 4;
                float acc = 0.f;
                for (int p = 0; p < 4; ++p) acc += u[p] * w2[p];
                emit(45 + j, acc);
            }
        } else {
            int i0 = i;
            float w[23];
#pragma unroll 1
            for (int p = 0; p < 23; ++p) w[p] = w3_0e[(s * 23 + p) * CC + c];
            int k = 0;
#pragma unroll 1
            for (int a = 0; a < 9; ++a)
#pragma unroll 1
                for (int b = a; b < 9; ++b) {
                    const float* ua = u3_0e + (size_t)(((i0 * 9 + a) * 9 + b)) * 23;
                    const float* ub = u3_0e + (size_t)(((i0 * 9 + b) * 9 + a)) * 23;
                    float acc = 0.f;
                    if (a == b) { for (int p = 0; p < 23; ++p) acc += ua[p] * w[p]; }
                    else        { for (int p = 0; p < 23; ++p) acc += (ua[p] + ub[p]) * w[p]; }
                    emit(k++, acc);
                }
            float w2[4];
#pragma unroll
            for (int p = 0; p < 4; ++p) w2[p] = w2_0e[(s * 4 + p) * CC + c];
#pragma unroll 1
            for (int j = 0; j < 9; ++j) {
                const float* u = u2_0e + (size_t)((i0 * 9 + j)) * 4;
                float acc = 0.f;
                for (int p = 0; p < 4; ++p) acc += u[p] * w2[p];
                emit(45 + j, acc);
            }
        }
    } else {
        int z = row - 36;
        if (z < 3) {
            float wv = w1_1o[s * CC + c];
#pragma unroll 1
            for (int i = 0; i < 9; ++i) emit(45 + i, u1_1o[z * 9 + i] * wv);
        } else {
            float wv = w1_0e[s * CC + c];
#pragma unroll 1
            for (int i = 0; i < 9; ++i) emit(45 + i, u1_0e[i] * wv);
        }
    }
}

// ---------------- prep: gk and lin as B-fragment streams (bf16) ----------------
// gkf: [(s*16+kt)][ck4][lane64][e8]; linf: [(part*8+kt)][ck4][lane64][e8]
__global__ __launch_bounds__(256) void k_prepf(
    const float* __restrict__ gk, const float* __restrict__ lin0,
    const float* __restrict__ lin1, u16* __restrict__ gkf, u16* __restrict__ linf) {
    int b = blockIdx.x, t = threadIdx.x, lane = t & 63, ck = t >> 6;
    if (b < 160) {
        int s = b >> 4, kt = b & 15;
        int k = kt * 16 + (lane & 15);
        u16* dst = gkf + (((size_t)b * 4 + ck) * 64 + lane) * 8;
        const float* src = gk + (size_t)s * CC * 256;
#pragma unroll
        for (int e = 0; e < 8; ++e) {
            int c = ck * 32 + ((lane >> 4) & 3) * 8 + e;
            dst[e] = bf16rne(src[c * 256 + k]);
        }
    } else {
        int bb = b - 160;            // part*8 + kt
        int kt = bb & 7;
        int k = kt * 16 + (lane & 15);
        const float* src = (bb >> 3) ? lin1 : lin0;
        u16* dst = linf + (((size_t)bb * 4 + ck) * 64 + lane) * 8;
#pragma unroll
        for (int e = 0; e < 8; ++e) {
            int c = ck * 32 + ((lane >> 4) & 3) * 8 + e;
            dst[e] = bf16rne(src[c * CC + k]);
        }
    }
}

// ---------------- symmetric contraction via MFMA ----------------
// block = 64 nodes x 1 channel, 256 thr. Wave w builds y slots [16w,16w+16)
// for all 64 nodes with STATIC tables; MFMA lanes read B-frags from LDS.
__global__ __launch_bounds__(256) void k_contract(
    const float* __restrict__ nf, const int* __restrict__ order,
    const int* __restrict__ blk_sp, const u16* __restrict__ af_g,
    float* __restrict__ f0t, float* __restrict__ f1t) {
    int tile = blockIdx.x;               // 0..319
    int c = blockIdx.y;
    int s = blk_sp[tile >> 4];
    if (s < 0) return;

    __shared__ __align__(16) u16 afl[AFRAG_U16];      // 6 KB
    __shared__ float xl[64 * 13];                     // 3.3 KB
    __shared__ __align__(16) unsigned yl[64 * 32];    // 8 KB (y bf16 pairs)
    __shared__ float Bl[4 * 16 * 43];                 // 11 KB

    int tid = threadIdx.x;
    int lane = tid & 63, wave = tid >> 6;
    int pos_base = tile * 64;

    // stage A-fragments (6 KB)
    {
        const uint4* ag = (const uint4*)(af_g + (size_t)(c * SS + s) * AFRAG_U16);
        uint4* al = (uint4*)afl;
        al[tid] = ag[tid];
        if (tid < 128) al[256 + tid] = ag[256 + tid];
    }
    // stage x (stride 13)
    {
        int n = order[pos_base + lane];
        const float* r = (n >= 0) ? (nf + (size_t)n * 1152) : nullptr;
        if (wave == 0) {
            xl[lane * 13 + 0] = r ? r[c] : 0.f;
        } else if (wave == 1) {
#pragma unroll
            for (int j = 0; j < 3; ++j) xl[lane * 13 + 1 + j] = r ? r[128 + c * 3 + j] : 0.f;
        } else if (wave == 2) {
#pragma unroll
            for (int j = 0; j < 2; ++j) xl[lane * 13 + 4 + j] = r ? r[512 + c * 5 + j] : 0.f;
        } else {
#pragma unroll
            for (int j = 2; j < 5; ++j) xl[lane * 13 + 4 + j] = r ? r[512 + c * 5 + j] : 0.f;
        }
    }
    __syncthreads();

    // ---- phase 1: build y for node=lane, slots [16*wave, 16*wave+16) ----
    {
        float xr[9];
#pragma unroll
        for (int i = 0; i < 9; ++i) xr[i] = xl[lane * 13 + i];
        int sw = (lane & 7) << 2;
#pragma unroll
        for (int w4 = 0; w4 < 4; ++w4) {
            if (wave == w4) {
                unsigned pk[8];
#pragma unroll
                for (int jj = 0; jj < 8; ++jj) {
                    const int s0 = w4 * 16 + 2 * jj, s1 = s0 + 1;
                    float v0 = (s0 < 45) ? xr[PA[s0]] * xr[PB[s0]]
                             : ((s0 < 54) ? xr[s0 - 45] : 0.f);
                    float v1 = (s1 < 45) ? xr[PA[s1]] * xr[PB[s1]]
                             : ((s1 < 54) ? xr[s1 - 45] : 0.f);
                    pk[jj] = (unsigned)bf16rne(v0) | ((unsigned)bf16rne(v1) << 16);
                }
                uint4 q0 = {pk[0], pk[1], pk[2], pk[3]};
                uint4 q1 = {pk[4], pk[5], pk[6], pk[7]};
                *(uint4*)&yl[lane * 32 + ((w4 * 8) ^ sw)] = q0;
                *(uint4*)&yl[lane * 32 + ((w4 * 8 + 4) ^ sw)] = q1;
            }
        }
    }
    __syncthreads();

    // ---- MFMA phase ----
    int n16 = lane & 15, g = lane >> 4;
    int myn = wave * 16 + n16;
    int sw2 = (n16 & 7) << 2;

    bf16x8 yf0 = *(const bf16x8*)&yl[myn * 32 + ((g * 4) ^ sw2)];
    bf16x8 yf1 = *(const bf16x8*)&yl[myn * 32 + ((16 + g * 4) ^ sw2)];

    f32x4 acc0 = {0.f, 0.f, 0.f, 0.f}, acc1 = acc0, acc2 = acc0;
    {
        const bf16x8* afv = (const bf16x8*)afl;
        acc0 = __builtin_amdgcn_mfma_f32_16x16x32_bf16(afv[0 * 64 + lane], yf0, acc0, 0, 0, 0);
        acc0 = __builtin_amdgcn_mfma_f32_16x16x32_bf16(afv[1 * 64 + lane], yf1, acc0, 0, 0, 0);
        acc1 = __builtin_amdgcn_mfma_f32_16x16x32_bf16(afv[2 * 64 + lane], yf0, acc1, 0, 0, 0);
        acc1 = __builtin_amdgcn_mfma_f32_16x16x32_bf16(afv[3 * 64 + lane], yf1, acc1, 0, 0, 0);
        acc2 = __builtin_amdgcn_mfma_f32_16x16x32_bf16(afv[4 * 64 + lane], yf0, acc2, 0, 0, 0);
        acc2 = __builtin_amdgcn_mfma_f32_16x16x32_bf16(afv[5 * 64 + lane], yf1, acc2, 0, 0, 0);
    }

    // scatter B rows (stride 43; per-wave buffer, intra-wave use only).
    // Rows 0..39 only: blk2 rows 40..47 are zero-padding and writing them
    // would overflow the 16*43 region (R5 bug).
    float* bw = &Bl[wave * 688];
#pragma unroll
    for (int r = 0; r < 4; ++r) bw[n16 * 43 + 0 * 16 + g * 4 + r] = acc0[r];
#pragma unroll
    for (int r = 0; r < 4; ++r) bw[n16 * 43 + 1 * 16 + g * 4 + r] = acc1[r];
    if (g < 2) {
#pragma unroll
        for (int r = 0; r < 4; ++r) bw[n16 * 43 + 2 * 16 + g * 4 + r] = acc2[r];
    }

    // epilogue: (node=myn, section=g): val = B[36+g] + sum_i B[g*9+i]*x_i
    float val = bw[n16 * 43 + 36 + g];
#pragma unroll
    for (int i = 0; i < 9; ++i) val += bw[n16 * 43 + g * 9 + i] * xl[myn * 13 + i];

    int pos = pos_base + myn;
    if (g == 3) f0t[(size_t)c * NPAD + pos] = val;
    else        f1t[(size_t)(c * 3 + g) * NPAD + pos] = val;
}

// ---------------- fused gate + equivariant linear (MFMA) ----------------
// block = 64 pos, 256 thr, 4 waves (wave = pt row-block).
#define GSTR 264
__global__ __launch_bounds__(256) void k_post(
    const float* __restrict__ f0t, const float* __restrict__ f1t,
    const u16* __restrict__ gkf, const u16* __restrict__ linf,
    const float* __restrict__ gb, const int* __restrict__ order,
    const int* __restrict__ blk_sp, float* __restrict__ out) {
    int tile = blockIdx.x;
    int s = blk_sp[tile >> 4];
    if (s < 0) return;
    int p0 = tile * 64;

    __shared__ __align__(16) u16 frag[4][4][64][8];   // 16 KB (A1, then A2)
    __shared__ __align__(16) u16 gate_l[64 * GSTR];   // 33 KB
    __shared__ int ord[64];

    int t = threadIdx.x, lane = t & 63, w = t >> 6;
    int l15 = lane & 15, lg = lane >> 4;
    if (t < 64) ord[t] = order[p0 + t];

    // stage A1 = scal (f0) bf16 fragments
#pragma unroll 1
    for (int it = 0; it < 32; ++it) {
        int posn = t & 63;
        int c = (t >> 6) + 4 * it;
        float v = f0t[(size_t)c * NPAD + p0 + posn];
        frag[posn >> 4][c >> 5][((c >> 3) & 3) * 16 + (posn & 15)][c & 7] = bf16rne(v);
    }
    __syncthreads();

    // GEMM1: gate[pos][k] = bias + sum_c scal[pos][c]*gk[c][k]
#pragma unroll 1
    for (int kt = 0; kt < 16; ++kt) {
        float bias = gb[s * 256 + kt * 16 + l15];
        f32x4 acc = {bias, bias, bias, bias};
#pragma unroll
        for (int ck = 0; ck < 4; ++ck) {
            bf16x8 a = *(const bf16x8*)&frag[w][ck][lane][0];
            bf16x8 b = *(const bf16x8*)&gkf[(((size_t)(s * 16 + kt)) * 4 + ck) * 512 + lane * 8];
            acc = __builtin_amdgcn_mfma_f32_16x16x32_bf16(a, b, acc, 0, 0, 0);
        }
#pragma unroll
        for (int r = 0; r < 4; ++r) {
            int posn = w * 16 + lg * 4 + r;
            gate_l[posn * GSTR + kt * 16 + l15] = bf16rne(acc[r]);
        }
    }
    __syncthreads();

    const float INV = 0.08838834764831845f;   // 1/sqrt(128)

    // GEMM2: p=0 -> f0*gate[:, :128] @ lin0 ; p=1..3 -> f1z*gate[:,128:] @ lin1
#pragma unroll 1
    for (int p = 0; p < 4; ++p) {
        // build A2 fragments
#pragma unroll 1
        for (int it = 0; it < 4; ++it) {
            int rr = it * 256 + t;                 // 0..1023
            int pt = rr >> 8, ck = (rr >> 6) & 3, l2 = rr & 63;
            int posn = pt * 16 + (l2 & 15);
            int cb = ck * 32 + (l2 >> 4) * 8;
            u16 res[8];
            if (p == 0) {
                bf16x8 a1 = *(const bf16x8*)&frag[pt][ck][l2][0];
                const u16* gp = &gate_l[posn * GSTR + cb];
#pragma unroll
                for (int e = 0; e < 8; ++e)
                    res[e] = bf16rne(bf2f((u16)a1[e]) * bf2f(gp[e]));
            } else {
                int z = p - 1;
                const u16* gp = &gate_l[posn * GSTR + 128 + cb];
#pragma unroll
                for (int e = 0; e < 8; ++e) {
                    float fv = f1t[((size_t)(cb + e) * 3 + z) * NPAD + p0 + posn];
                    res[e] = bf16rne(fv * bf2f(gp[e]));
                }
            }
            uint4 uv;
            uv.x = (unsigned)res[0] | ((unsigned)res[1] << 16);
            uv.y = (unsigned)res[2] | ((unsigned)res[3] << 16);
            uv.z = (unsigned)res[4] | ((unsigned)res[5] << 16);
            uv.w = (unsigned)res[6] | ((unsigned)res[7] << 16);
            *(uint4*)&frag[pt][ck][l2][0] = uv;
        }
        __syncthreads();

        int lbase = (p == 0) ? 0 : 8;
#pragma unroll 1
        for (int kt = 0; kt < 8; ++kt) {
            f32x4 acc = {0.f, 0.f, 0.f, 0.f};
#pragma unroll
            for (int ck = 0; ck < 4; ++ck) {
                bf16x8 a = *(const bf16x8*)&frag[w][ck][lane][0];
                bf16x8 b = *(const bf16x8*)&linf[(((size_t)(lbase + kt)) * 4 + ck) * 512 + lane * 8];
                acc = __builtin_amdgcn_mfma_f32_16x16x32_bf16(a, b, acc, 0, 0, 0);
            }
            int k = kt * 16 + l15;
            int kk = (p == 0) ? k : (128 + k * 3 + (p - 1));
#pragma unroll
            for (int r = 0; r < 4; ++r) {
                int posn = w * 16 + lg * 4 + r;
                int n = ord[posn];
                if (n >= 0) out[(size_t)n * 512 + kk] = acc[r] * INV;
            }
        }
        __syncthreads();
    }
}

// ---------------------------------------------------------------------------
extern "C" void kernel_launch(void* const* d_in, const int* in_sizes, int n_in,
                              void* d_out, int out_size, void* d_ws, size_t ws_size,
                              hipStream_t stream) {
    const float* nf    = (const float*)d_in[0];
    const int*   sp    = (const int*)  d_in[1];
    const float* u1_0e = (const float*)d_in[2];
    const float* u2_0e = (const float*)d_in[3];
    const float* u3_0e = (const float*)d_in[4];
    const float* u1_1o = (const float*)d_in[5];
    const float* u2_1o = (const float*)d_in[6];
    const float* u3_1o = (const float*)d_in[7];
    const float* w1_0e = (const float*)d_in[8];
    const float* w2_0e = (const float*)d_in[9];
    const float* w3_0e = (const float*)d_in[10];
    const float* w1_1o = (const float*)d_in[11];
    const float* w2_1o = (const float*)d_in[12];
    const float* w3_1o = (const float*)d_in[13];
    const float* gk    = (const float*)d_in[14];
    const float* gb    = (const float*)d_in[15];
    const float* lin0  = (const float*)d_in[16];
    const float* lin1  = (const float*)d_in[17];

    float* ws   = (float*)d_ws;
    u16*  af    = (u16*)(ws + OFF_AF);
    float* f0t  = ws + OFF_F0;
    float* f1t  = ws + OFF_F1;
    u16*  gkf   = (u16*)(ws + OFF_GKF);
    u16*  linf  = (u16*)(ws + OFF_LINF);
    int* order  = (int*)(ws + OFF_ORD);
    int* meta   = (int*)(ws + OFF_META);
    int* counts = meta;
    int* cursor = meta + 16;
    int* blk_sp = meta + 32;

    hipMemsetAsync(counts, 0, 16 * sizeof(int), stream);
    hipMemsetAsync(order, 0xFF, NPAD * sizeof(int), stream);
    hipMemsetAsync(af, 0, (size_t)CC * SS * AFRAG_U16 * sizeof(u16), stream);

    k_hist<<<40, 256, 0, stream>>>(sp, counts);
    k_plan<<<1, 64, 0, stream>>>(counts, cursor, blk_sp);
    k_scatter<<<40, 256, 0, stream>>>(sp, cursor, order);
    dim3 gp(40, SS);
    k_prep2<<<gp, 128, 0, stream>>>(u1_0e, u2_0e, u3_0e, u1_1o, u2_1o, u3_1o,
                                    w1_0e, w2_0e, w3_0e, w1_1o, w2_1o, w3_1o, af);
    k_prepf<<<176, 256, 0, stream>>>(gk, lin0, lin1, gkf, linf);
    dim3 gm(NPAD / 64, CC);
    k_contract<<<gm, 256, 0, stream>>>(nf, order, blk_sp, af, f0t, f1t);
    k_post<<<NPAD / 64, 256, 0, stream>>>(f0t, f1t, gkf, linf, gb, order, blk_sp,
                                          (float*)d_out);
}

// Round 7
// 219.058 us; speedup vs baseline: 3.0063x; 1.0461x over previous
//
#include <hip/hip_runtime.h>

// ---------------------------------------------------------------------------
// EquivariantProductBasisBlock (MACE symmetric contraction + gate + linear)
// N=10000, C=128, D=9, S=10.
// R7 = R6 with k_contract processing 256 nodes/block (4 subtiles), A-frags
// preloaded into registers and reused across subtiles. 40960 -> 10240 blocks.
// ---------------------------------------------------------------------------

#define NN 10000
#define CC 128
#define SS 10
#define NPB 1024
#define MAXBLK 20
#define NPAD (MAXBLK*NPB)        // 20480

typedef unsigned short u16;
typedef __attribute__((ext_vector_type(8))) short bf16x8;
typedef __attribute__((ext_vector_type(4))) float f32x4;

// sym-pair tables for y slots 0..44 (a<=b); slots 45..53 = linear x_j; 54+ = 0
__device__ constexpr int PA[45] = {
    0,0,0,0,0,0,0,0,0,
    1,1,1,1,1,1,1,1,
    2,2,2,2,2,2,2,
    3,3,3,3,3,3,
    4,4,4,4,4,
    5,5,5,5,
    6,6,6,
    7,7,
    8};
__device__ constexpr int PB[45] = {
    0,1,2,3,4,5,6,7,8,
    1,2,3,4,5,6,7,8,
    2,3,4,5,6,7,8,
    3,4,5,6,7,8,
    4,5,6,7,8,
    5,6,7,8,
    6,7,8,
    7,8,
    8};

// A-frag layout per (c,s): [blk3][kh2][lane64][e8] bf16 = 3072 u16 = 6KB.
//   element = M[row = blk*16 + (lane&15)][k = kh*32 + (lane>>4)*8 + e]
#define AFRAG_U16 3072

// ws layout (floats)
#define OFF_AF   0                          // 1280*3072 u16 = 1,966,080 f
#define OFF_F0   1966080                    // CC*NPAD   = 2,621,440
#define OFF_F1   4587520                    // 3*CC*NPAD = 7,864,320
#define OFF_GKF  12451840                   // 327,680 u16 = 163,840 f
#define OFF_LINF 12615680                   // 32,768 u16 = 16,384 f
#define OFF_ORD  12632064                   // NPAD ints
#define OFF_META (OFF_ORD + NPAD)           // 64 ints
// total = 12,652,608 floats = 50.6 MB

__device__ __forceinline__ u16 bf16rne(float f) {
    unsigned u = __float_as_uint(f);
    u += 0x7fffu + ((u >> 16) & 1u);
    return (u16)(u >> 16);
}
__device__ __forceinline__ float bf2f(u16 h) {
    return __uint_as_float(((unsigned)h) << 16);
}

// ---------------- species bucketing ----------------
__global__ void k_hist(const int* __restrict__ sp, int* __restrict__ counts) {
    int n = blockIdx.x * 256 + threadIdx.x;
    if (n < NN) atomicAdd(&counts[sp[n]], 1);
}

__global__ void k_plan(const int* __restrict__ counts, int* __restrict__ cursor,
                       int* __restrict__ blk_sp) {
    if (threadIdx.x != 0) return;
    int pos = 0, b = 0;
    for (int s = 0; s < SS; ++s) {
        cursor[s] = pos;
        int nb = (counts[s] + NPB - 1) / NPB;
        for (int i = 0; i < nb; ++i) blk_sp[b++] = s;
        pos += nb * NPB;
    }
    for (; b < MAXBLK; ++b) blk_sp[b] = -1;
}

__global__ void k_scatter(const int* __restrict__ sp, int* __restrict__ cursor,
                          int* __restrict__ order) {
    int n = blockIdx.x * 256 + threadIdx.x;
    if (n < NN) {
        int p = atomicAdd(&cursor[sp[n]], 1);
        order[p] = n;
    }
}

// ---------------- prep: build M in A-fragment layout (bf16) ----------------
__global__ __launch_bounds__(128) void k_prep2(
    const float* __restrict__ u1_0e, const float* __restrict__ u2_0e, const float* __restrict__ u3_0e,
    const float* __restrict__ u1_1o, const float* __restrict__ u2_1o, const float* __restrict__ u3_1o,
    const float* __restrict__ w1_0e, const float* __restrict__ w2_0e, const float* __restrict__ w3_0e,
    const float* __restrict__ w1_1o, const float* __restrict__ w2_1o, const float* __restrict__ w3_1o,
    u16* __restrict__ af) {
    int row = blockIdx.x, s = blockIdx.y, c = threadIdx.x;
    u16* base = af + (size_t)(c * SS + s) * AFRAG_U16;
    int blk = row >> 4, r16 = row & 15;
    auto emit = [&](int k, float v) {
        int kh = k >> 5, kr = k & 31, g = kr >> 3, e = k & 7;
        base[(((blk * 2 + kh) * 64 + g * 16 + r16) << 3) + e] = bf16rne(v);
    };
    if (row < 36) {
        int sec = row / 9, i = row % 9;
        if (sec < 3) {
            float w[30];
#pragma unroll 1
            for (int p = 0; p < 30; ++p) w[p] = w3_1o[(s * 30 + p) * CC + c];
            int k = 0;
#pragma unroll 1
            for (int a = 0; a < 9; ++a)
#pragma unroll 1
                for (int b = a; b < 9; ++b) {
                    const float* ua = u3_1o + (size_t)((((sec * 9 + i) * 9 + a) * 9 + b)) * 30;
                    const float* ub = u3_1o + (size_t)((((sec * 9 + i) * 9 + b) * 9 + a)) * 30;
                    float acc = 0.f;
                    if (a == b) { for (int p = 0; p < 30; ++p) acc += ua[p] * w[p]; }
                    else        { for (int p = 0; p < 30; ++p) acc += (ua[p] + ub[p]) * w[p]; }
                    emit(k++, acc);
                }
            float w2[4];
#pragma unroll
            for (int p = 0; p < 4; ++p) w2[p] = w2_1o[(s * 4 + p) * CC + c];
#pragma unroll 1
            for (int j = 0; j < 9; ++j) {
                const float* u = u2_1o + (size_t)(((sec * 9 + i) * 9 + j)) * 4;
                float acc = 0.f;
                for (int p = 0; p < 4; ++p) acc += u[p] * w2[p];
                emit(45 + j, acc);
            }
        } else {
            int i0 = i;
            float w[23];
#pragma unroll 1
            for (int p = 0; p < 23; ++p) w[p] = w3_0e[(s * 23 + p) * CC + c];
            int k = 0;
#pragma unroll 1
            for (int a = 0; a < 9; ++a)
#pragma unroll 1
                for (int b = a; b < 9; ++b) {
                    const float* ua = u3_0e + (size_t)(((i0 * 9 + a) * 9 + b)) * 23;
                    const float* ub = u3_0e + (size_t)(((i0 * 9 + b) * 9 + a)) * 23;
                    float acc = 0.f;
                    if (a == b) { for (int p = 0; p < 23; ++p) acc += ua[p] * w[p]; }
                    else        { for (int p = 0; p < 23; ++p) acc += (ua[p] + ub[p]) * w[p]; }
                    emit(k++, acc);
                }
            float w2[4];
#pragma unroll
            for (int p = 0; p < 4; ++p) w2[p] = w2_0e[(s * 4 + p) * CC + c];
#pragma unroll 1
            for (int j = 0; j < 9; ++j) {
                const float* u = u2_0e + (size_t)((i0 * 9 + j)) * 4;
                float acc = 0.f;
                for (int p = 0; p < 4; ++p) acc += u[p] * w2[p];
                emit(45 + j, acc);
            }
        }
    } else {
        int z = row - 36;
        if (z < 3) {
            float wv = w1_1o[s * CC + c];
#pragma unroll 1
            for (int i = 0; i < 9; ++i) emit(45 + i, u1_1o[z * 9 + i] * wv);
        } else {
            float wv = w1_0e[s * CC + c];
#pragma unroll 1
            for (int i = 0; i < 9; ++i) emit(45 + i, u1_0e[i] * wv);
        }
    }
}

// ---------------- prep: gk and lin as B-fragment streams (bf16) ----------------
// gkf: [(s*16+kt)][ck4][lane64][e8]; linf: [(part*8+kt)][ck4][lane64][e8]
__global__ __launch_bounds__(256) void k_prepf(
    const float* __restrict__ gk, const float* __restrict__ lin0,
    const float* __restrict__ lin1, u16* __restrict__ gkf, u16* __restrict__ linf) {
    int b = blockIdx.x, t = threadIdx.x, lane = t & 63, ck = t >> 6;
    if (b < 160) {
        int s = b >> 4, kt = b & 15;
        int k = kt * 16 + (lane & 15);
        u16* dst = gkf + (((size_t)b * 4 + ck) * 64 + lane) * 8;
        const float* src = gk + (size_t)s * CC * 256;
#pragma unroll
        for (int e = 0; e < 8; ++e) {
            int c = ck * 32 + ((lane >> 4) & 3) * 8 + e;
            dst[e] = bf16rne(src[c * 256 + k]);
        }
    } else {
        int bb = b - 160;            // part*8 + kt
        int kt = bb & 7;
        int k = kt * 16 + (lane & 15);
        const float* src = (bb >> 3) ? lin1 : lin0;
        u16* dst = linf + (((size_t)bb * 4 + ck) * 64 + lane) * 8;
#pragma unroll
        for (int e = 0; e < 8; ++e) {
            int c = ck * 32 + ((lane >> 4) & 3) * 8 + e;
            dst[e] = bf16rne(src[c * CC + k]);
        }
    }
}

// ---------------- symmetric contraction via MFMA ----------------
// block = 256 nodes x 1 channel, 256 thr, 4 subtiles of 64 nodes.
// A-frags preloaded to registers once; per subtile: stage x, build y (static
// tables, per-wave slot ranges), 6 MFMAs, B scatter, fp32 epilogue.
__global__ __launch_bounds__(256) void k_contract(
    const float* __restrict__ nf, const int* __restrict__ order,
    const int* __restrict__ blk_sp, const u16* __restrict__ af_g,
    float* __restrict__ f0t, float* __restrict__ f1t) {
    int btile = blockIdx.x;              // 0..79 (256-node groups)
    int c = blockIdx.y;
    int s = blk_sp[btile >> 2];          // 4 btiles per 1024-node segment
    if (s < 0) return;

    __shared__ __align__(16) u16 afl[AFRAG_U16];      // 6 KB
    __shared__ float xl[64 * 13];                     // 3.3 KB
    __shared__ __align__(16) unsigned yl[64 * 32];    // 8 KB (y bf16 pairs)
    __shared__ float Bl[4 * 16 * 43];                 // 11 KB

    int tid = threadIdx.x;
    int lane = tid & 63, wave = tid >> 6;

    // stage A-fragments (6 KB), then preload to registers
    {
        const uint4* ag = (const uint4*)(af_g + (size_t)(c * SS + s) * AFRAG_U16);
        uint4* al = (uint4*)afl;
        al[tid] = ag[tid];
        if (tid < 128) al[256 + tid] = ag[256 + tid];
    }
    __syncthreads();

    bf16x8 areg0, areg1, areg2, areg3, areg4, areg5;
    {
        const bf16x8* afv = (const bf16x8*)afl;
        areg0 = afv[0 * 64 + lane]; areg1 = afv[1 * 64 + lane];
        areg2 = afv[2 * 64 + lane]; areg3 = afv[3 * 64 + lane];
        areg4 = afv[4 * 64 + lane]; areg5 = afv[5 * 64 + lane];
    }

    int n16 = lane & 15, g = lane >> 4;
    int myn = wave * 16 + n16;
    int sw2 = (n16 & 7) << 2;
    float* bw = &Bl[wave * 688];

#pragma unroll 1
    for (int sub = 0; sub < 4; ++sub) {
        int pos_base = btile * 256 + sub * 64;

        // stage x (stride 13); element-sets split across waves
        {
            int n = order[pos_base + lane];
            const float* r = (n >= 0) ? (nf + (size_t)n * 1152) : nullptr;
            if (wave == 0) {
                xl[lane * 13 + 0] = r ? r[c] : 0.f;
            } else if (wave == 1) {
#pragma unroll
                for (int j = 0; j < 3; ++j) xl[lane * 13 + 1 + j] = r ? r[128 + c * 3 + j] : 0.f;
            } else if (wave == 2) {
#pragma unroll
                for (int j = 0; j < 2; ++j) xl[lane * 13 + 4 + j] = r ? r[512 + c * 5 + j] : 0.f;
            } else {
#pragma unroll
                for (int j = 2; j < 5; ++j) xl[lane * 13 + 4 + j] = r ? r[512 + c * 5 + j] : 0.f;
            }
        }
        __syncthreads();

        // build y for node=lane, slots [16*wave, 16*wave+16) (static tables)
        {
            float xr[9];
#pragma unroll
            for (int i = 0; i < 9; ++i) xr[i] = xl[lane * 13 + i];
            int sw = (lane & 7) << 2;
#pragma unroll
            for (int w4 = 0; w4 < 4; ++w4) {
                if (wave == w4) {
                    unsigned pk[8];
#pragma unroll
                    for (int jj = 0; jj < 8; ++jj) {
                        const int s0 = w4 * 16 + 2 * jj, s1 = s0 + 1;
                        float v0 = (s0 < 45) ? xr[PA[s0]] * xr[PB[s0]]
                                 : ((s0 < 54) ? xr[s0 - 45] : 0.f);
                        float v1 = (s1 < 45) ? xr[PA[s1]] * xr[PB[s1]]
                                 : ((s1 < 54) ? xr[s1 - 45] : 0.f);
                        pk[jj] = (unsigned)bf16rne(v0) | ((unsigned)bf16rne(v1) << 16);
                    }
                    uint4 q0 = {pk[0], pk[1], pk[2], pk[3]};
                    uint4 q1 = {pk[4], pk[5], pk[6], pk[7]};
                    *(uint4*)&yl[lane * 32 + ((w4 * 8) ^ sw)] = q0;
                    *(uint4*)&yl[lane * 32 + ((w4 * 8 + 4) ^ sw)] = q1;
                }
            }
        }
        __syncthreads();

        // MFMA (registers A) + B scatter + epilogue
        bf16x8 yf0 = *(const bf16x8*)&yl[myn * 32 + ((g * 4) ^ sw2)];
        bf16x8 yf1 = *(const bf16x8*)&yl[myn * 32 + ((16 + g * 4) ^ sw2)];

        f32x4 acc0 = {0.f, 0.f, 0.f, 0.f}, acc1 = acc0, acc2 = acc0;
        acc0 = __builtin_amdgcn_mfma_f32_16x16x32_bf16(areg0, yf0, acc0, 0, 0, 0);
        acc0 = __builtin_amdgcn_mfma_f32_16x16x32_bf16(areg1, yf1, acc0, 0, 0, 0);
        acc1 = __builtin_amdgcn_mfma_f32_16x16x32_bf16(areg2, yf0, acc1, 0, 0, 0);
        acc1 = __builtin_amdgcn_mfma_f32_16x16x32_bf16(areg3, yf1, acc1, 0, 0, 0);
        acc2 = __builtin_amdgcn_mfma_f32_16x16x32_bf16(areg4, yf0, acc2, 0, 0, 0);
        acc2 = __builtin_amdgcn_mfma_f32_16x16x32_bf16(areg5, yf1, acc2, 0, 0, 0);

        // rows 0..39 only (blk2 rows 40..47 are pad; R5 overflow lesson)
#pragma unroll
        for (int r = 0; r < 4; ++r) bw[n16 * 43 + 0 * 16 + g * 4 + r] = acc0[r];
#pragma unroll
        for (int r = 0; r < 4; ++r) bw[n16 * 43 + 1 * 16 + g * 4 + r] = acc1[r];
        if (g < 2) {
#pragma unroll
            for (int r = 0; r < 4; ++r) bw[n16 * 43 + 2 * 16 + g * 4 + r] = acc2[r];
        }

        float val = bw[n16 * 43 + 36 + g];
#pragma unroll
        for (int i = 0; i < 9; ++i) val += bw[n16 * 43 + g * 9 + i] * xl[myn * 13 + i];

        int pos = pos_base + myn;
        if (g == 3) f0t[(size_t)c * NPAD + pos] = val;
        else        f1t[(size_t)(c * 3 + g) * NPAD + pos] = val;
        __syncthreads();   // protect xl/yl before next subtile overwrites
    }
}

// ---------------- fused gate + equivariant linear (MFMA) ----------------
// block = 64 pos, 256 thr, 4 waves (wave = pt row-block).
#define GSTR 264
__global__ __launch_bounds__(256) void k_post(
    const float* __restrict__ f0t, const float* __restrict__ f1t,
    const u16* __restrict__ gkf, const u16* __restrict__ linf,
    const float* __restrict__ gb, const int* __restrict__ order,
    const int* __restrict__ blk_sp, float* __restrict__ out) {
    int tile = blockIdx.x;
    int s = blk_sp[tile >> 4];
    if (s < 0) return;
    int p0 = tile * 64;

    __shared__ __align__(16) u16 frag[4][4][64][8];   // 16 KB (A1, then A2)
    __shared__ __align__(16) u16 gate_l[64 * GSTR];   // 33 KB
    __shared__ int ord[64];

    int t = threadIdx.x, lane = t & 63, w = t >> 6;
    int l15 = lane & 15, lg = lane >> 4;
    if (t < 64) ord[t] = order[p0 + t];

    // stage A1 = scal (f0) bf16 fragments
#pragma unroll 1
    for (int it = 0; it < 32; ++it) {
        int posn = t & 63;
        int c = (t >> 6) + 4 * it;
        float v = f0t[(size_t)c * NPAD + p0 + posn];
        frag[posn >> 4][c >> 5][((c >> 3) & 3) * 16 + (posn & 15)][c & 7] = bf16rne(v);
    }
    __syncthreads();

    // GEMM1: gate[pos][k] = bias + sum_c scal[pos][c]*gk[c][k]
#pragma unroll 1
    for (int kt = 0; kt < 16; ++kt) {
        float bias = gb[s * 256 + kt * 16 + l15];
        f32x4 acc = {bias, bias, bias, bias};
#pragma unroll
        for (int ck = 0; ck < 4; ++ck) {
            bf16x8 a = *(const bf16x8*)&frag[w][ck][lane][0];
            bf16x8 b = *(const bf16x8*)&gkf[(((size_t)(s * 16 + kt)) * 4 + ck) * 512 + lane * 8];
            acc = __builtin_amdgcn_mfma_f32_16x16x32_bf16(a, b, acc, 0, 0, 0);
        }
#pragma unroll
        for (int r = 0; r < 4; ++r) {
            int posn = w * 16 + lg * 4 + r;
            gate_l[posn * GSTR + kt * 16 + l15] = bf16rne(acc[r]);
        }
    }
    __syncthreads();

    const float INV = 0.08838834764831845f;   // 1/sqrt(128)

    // GEMM2: p=0 -> f0*gate[:, :128] @ lin0 ; p=1..3 -> f1z*gate[:,128:] @ lin1
#pragma unroll 1
    for (int p = 0; p < 4; ++p) {
        // build A2 fragments
#pragma unroll 1
        for (int it = 0; it < 4; ++it) {
            int rr = it * 256 + t;                 // 0..1023
            int pt = rr >> 8, ck = (rr >> 6) & 3, l2 = rr & 63;
            int posn = pt * 16 + (l2 & 15);
            int cb = ck * 32 + (l2 >> 4) * 8;
            u16 res[8];
            if (p == 0) {
                bf16x8 a1 = *(const bf16x8*)&frag[pt][ck][l2][0];
                const u16* gp = &gate_l[posn * GSTR + cb];
#pragma unroll
                for (int e = 0; e < 8; ++e)
                    res[e] = bf16rne(bf2f((u16)a1[e]) * bf2f(gp[e]));
            } else {
                int z = p - 1;
                const u16* gp = &gate_l[posn * GSTR + 128 + cb];
#pragma unroll
                for (int e = 0; e < 8; ++e) {
                    float fv = f1t[((size_t)(cb + e) * 3 + z) * NPAD + p0 + posn];
                    res[e] = bf16rne(fv * bf2f(gp[e]));
                }
            }
            uint4 uv;
            uv.x = (unsigned)res[0] | ((unsigned)res[1] << 16);
            uv.y = (unsigned)res[2] | ((unsigned)res[3] << 16);
            uv.z = (unsigned)res[4] | ((unsigned)res[5] << 16);
            uv.w = (unsigned)res[6] | ((unsigned)res[7] << 16);
            *(uint4*)&frag[pt][ck][l2][0] = uv;
        }
        __syncthreads();

        int lbase = (p == 0) ? 0 : 8;
#pragma unroll 1
        for (int kt = 0; kt < 8; ++kt) {
            f32x4 acc = {0.f, 0.f, 0.f, 0.f};
#pragma unroll
            for (int ck = 0; ck < 4; ++ck) {
                bf16x8 a = *(const bf16x8*)&frag[w][ck][lane][0];
                bf16x8 b = *(const bf16x8*)&linf[(((size_t)(lbase + kt)) * 4 + ck) * 512 + lane * 8];
                acc = __builtin_amdgcn_mfma_f32_16x16x32_bf16(a, b, acc, 0, 0, 0);
            }
            int k = kt * 16 + l15;
            int kk = (p == 0) ? k : (128 + k * 3 + (p - 1));
#pragma unroll
            for (int r = 0; r < 4; ++r) {
                int posn = w * 16 + lg * 4 + r;
                int n = ord[posn];
                if (n >= 0) out[(size_t)n * 512 + kk] = acc[r] * INV;
            }
        }
        __syncthreads();
    }
}

// ---------------------------------------------------------------------------
extern "C" void kernel_launch(void* const* d_in, const int* in_sizes, int n_in,
                              void* d_out, int out_size, void* d_ws, size_t ws_size,
                              hipStream_t stream) {
    const float* nf    = (const float*)d_in[0];
    const int*   sp    = (const int*)  d_in[1];
    const float* u1_0e = (const float*)d_in[2];
    const float* u2_0e = (const float*)d_in[3];
    const float* u3_0e = (const float*)d_in[4];
    const float* u1_1o = (const float*)d_in[5];
    const float* u2_1o = (const float*)d_in[6];
    const float* u3_1o = (const float*)d_in[7];
    const float* w1_0e = (const float*)d_in[8];
    const float* w2_0e = (const float*)d_in[9];
    const float* w3_0e = (const float*)d_in[10];
    const float* w1_1o = (const float*)d_in[11];
    const float* w2_1o = (const float*)d_in[12];
    const float* w3_1o = (const float*)d_in[13];
    const float* gk    = (const float*)d_in[14];
    const float* gb    = (const float*)d_in[15];
    const float* lin0  = (const float*)d_in[16];
    const float* lin1  = (const float*)d_in[17];

    float* ws   = (float*)d_ws;
    u16*  af    = (u16*)(ws + OFF_AF);
    float* f0t  = ws + OFF_F0;
    float* f1t  = ws + OFF_F1;
    u16*  gkf   = (u16*)(ws + OFF_GKF);
    u16*  linf  = (u16*)(ws + OFF_LINF);
    int* order  = (int*)(ws + OFF_ORD);
    int* meta   = (int*)(ws + OFF_META);
    int* counts = meta;
    int* cursor = meta + 16;
    int* blk_sp = meta + 32;

    hipMemsetAsync(counts, 0, 16 * sizeof(int), stream);
    hipMemsetAsync(order, 0xFF, NPAD * sizeof(int), stream);
    hipMemsetAsync(af, 0, (size_t)CC * SS * AFRAG_U16 * sizeof(u16), stream);

    k_hist<<<40, 256, 0, stream>>>(sp, counts);
    k_plan<<<1, 64, 0, stream>>>(counts, cursor, blk_sp);
    k_scatter<<<40, 256, 0, stream>>>(sp, cursor, order);
    dim3 gp(40, SS);
    k_prep2<<<gp, 128, 0, stream>>>(u1_0e, u2_0e, u3_0e, u1_1o, u2_1o, u3_1o,
                                    w1_0e, w2_0e, w3_0e, w1_1o, w2_1o, w3_1o, af);
    k_prepf<<<176, 256, 0, stream>>>(gk, lin0, lin1, gkf, linf);
    dim3 gm(NPAD / 256, CC);
    k_contract<<<gm, 256, 0, stream>>>(nf, order, blk_sp, af, f0t, f1t);
    k_post<<<NPAD / 64, 256, 0, stream>>>(f0t, f1t, gkf, linf, gb, order, blk_sp,
                                          (float*)d_out);
}

// Round 8
// 192.561 us; speedup vs baseline: 3.4200x; 1.1376x over previous
//
#include <hip/hip_runtime.h>

// ---------------------------------------------------------------------------
// EquivariantProductBasisBlock (MACE symmetric contraction + gate + linear)
// N=10000, C=128, D=9, S=10.
// R8: k_contract = 1024-node segment/block, 16 subtiles, pipelined x-gather
// (ordl in LDS, x prefetched into regs during MFMA phase), yl bank-swizzle
// (stride 40 + perm XOR). Launch count 10 -> 6 (k_plan absorbs hist+memsets,
// k_prep2 zero-fills pad -> no af memset).
// ---------------------------------------------------------------------------

#define NN 10000
#define CC 128
#define SS 10
#define NPB 1024
#define MAXBLK 20
#define NPAD (MAXBLK*NPB)        // 20480

typedef unsigned short u16;
typedef __attribute__((ext_vector_type(8))) short bf16x8;
typedef __attribute__((ext_vector_type(4))) float f32x4;

// sym-pair tables for y slots 0..44 (a<=b); slots 45..53 = linear x_j; 54+ = 0
__device__ constexpr int PA[45] = {
    0,0,0,0,0,0,0,0,0,
    1,1,1,1,1,1,1,1,
    2,2,2,2,2,2,2,
    3,3,3,3,3,3,
    4,4,4,4,4,
    5,5,5,5,
    6,6,6,
    7,7,
    8};
__device__ constexpr int PB[45] = {
    0,1,2,3,4,5,6,7,8,
    1,2,3,4,5,6,7,8,
    2,3,4,5,6,7,8,
    3,4,5,6,7,8,
    4,5,6,7,8,
    5,6,7,8,
    6,7,8,
    7,8,
    8};

// A-frag layout per (c,s): [blk3][kh2][lane64][e8] bf16 = 3072 u16 = 6KB.
//   element = M[row = blk*16 + (lane&15)][k = kh*32 + (lane>>4)*8 + e]
#define AFRAG_U16 3072

// ws layout (floats)
#define OFF_AF   0                          // 1280*3072 u16 = 1,966,080 f
#define OFF_F0   1966080                    // CC*NPAD   = 2,621,440
#define OFF_F1   4587520                    // 3*CC*NPAD = 7,864,320
#define OFF_GKF  12451840                   // 327,680 u16 = 163,840 f
#define OFF_LINF 12615680                   // 32,768 u16 = 16,384 f
#define OFF_ORD  12632064                   // NPAD ints
#define OFF_META (OFF_ORD + NPAD)           // 64 ints
// total = 12,652,608 floats = 50.6 MB

__device__ __forceinline__ u16 bf16rne(float f) {
    unsigned u = __float_as_uint(f);
    u += 0x7fffu + ((u >> 16) & 1u);
    return (u16)(u >> 16);
}
__device__ __forceinline__ float bf2f(u16 h) {
    return __uint_as_float(((unsigned)h) << 16);
}

// ---------------- plan: species histogram + segment map + order init ----------------
__global__ __launch_bounds__(256) void k_plan(
    const int* __restrict__ sp, int* __restrict__ cursor,
    int* __restrict__ blk_sp, int* __restrict__ order) {
    __shared__ int cnt[SS];
    int t = threadIdx.x;
    if (t < SS) cnt[t] = 0;
    __syncthreads();
    for (int i = t; i < NN; i += 256) atomicAdd(&cnt[sp[i]], 1);
    __syncthreads();
    if (t == 0) {
        int pos = 0, b = 0;
        for (int s = 0; s < SS; ++s) {
            cursor[s] = pos;
            int nb = (cnt[s] + NPB - 1) / NPB;
            for (int i = 0; i < nb; ++i) blk_sp[b++] = s;
            pos += nb * NPB;
        }
        for (; b < MAXBLK; ++b) blk_sp[b] = -1;
    }
    for (int i = t; i < NPAD; i += 256) order[i] = -1;
}

__global__ void k_scatter(const int* __restrict__ sp, int* __restrict__ cursor,
                          int* __restrict__ order) {
    int n = blockIdx.x * 256 + threadIdx.x;
    if (n < NN) {
        int p = atomicAdd(&cursor[sp[n]], 1);
        order[p] = n;
    }
}

// ---------------- prep: build M in A-fragment layout (bf16) ----------------
// grid (48 rows, 10 s) x 128 thr(c). Rows 40..47 + pad k-slots zero-filled
// here (replaces the af memset).
__global__ __launch_bounds__(128) void k_prep2(
    const float* __restrict__ u1_0e, const float* __restrict__ u2_0e, const float* __restrict__ u3_0e,
    const float* __restrict__ u1_1o, const float* __restrict__ u2_1o, const float* __restrict__ u3_1o,
    const float* __restrict__ w1_0e, const float* __restrict__ w2_0e, const float* __restrict__ w3_0e,
    const float* __restrict__ w1_1o, const float* __restrict__ w2_1o, const float* __restrict__ w3_1o,
    u16* __restrict__ af) {
    int row = blockIdx.x, s = blockIdx.y, c = threadIdx.x;
    u16* base = af + (size_t)(c * SS + s) * AFRAG_U16;
    int blk = row >> 4, r16 = row & 15;
    auto emit = [&](int k, float v) {
        int kh = k >> 5, kr = k & 31, g = kr >> 3, e = k & 7;
        base[(((blk * 2 + kh) * 64 + g * 16 + r16) << 3) + e] = bf16rne(v);
    };
    if (row < 36) {
        for (int k = 54; k < 64; ++k) emit(k, 0.f);
        int sec = row / 9, i = row % 9;
        if (sec < 3) {
            float w[30];
#pragma unroll 1
            for (int p = 0; p < 30; ++p) w[p] = w3_1o[(s * 30 + p) * CC + c];
            int k = 0;
#pragma unroll 1
            for (int a = 0; a < 9; ++a)
#pragma unroll 1
                for (int b = a; b < 9; ++b) {
                    const float* ua = u3_1o + (size_t)((((sec * 9 + i) * 9 + a) * 9 + b)) * 30;
                    const float* ub = u3_1o + (size_t)((((sec * 9 + i) * 9 + b) * 9 + a)) * 30;
                    float acc = 0.f;
                    if (a == b) { for (int p = 0; p < 30; ++p) acc += ua[p] * w[p]; }
                    else        { for (int p = 0; p < 30; ++p) acc += (ua[p] + ub[p]) * w[p]; }
                    emit(k++, acc);
                }
            float w2[4];
#pragma unroll
            for (int p = 0; p < 4; ++p) w2[p] = w2_1o[(s * 4 + p) * CC + c];
#pragma unroll 1
            for (int j = 0; j < 9; ++j) {
                const float* u = u2_1o + (size_t)(((sec * 9 + i) * 9 + j)) * 4;
                float acc = 0.f;
                for (int p = 0; p < 4; ++p) acc += u[p] * w2[p];
                emit(45 + j, acc);
            }
        } else {
            int i0 = i;
            float w[23];
#pragma unroll 1
            for (int p = 0; p < 23; ++p) w[p] = w3_0e[(s * 23 + p) * CC + c];
            int k = 0;
#pragma unroll 1
            for (int a = 0; a < 9; ++a)
#pragma unroll 1
                for (int b = a; b < 9; ++b) {
                    const float* ua = u3_0e + (size_t)(((i0 * 9 + a) * 9 + b)) * 23;
                    const float* ub = u3_0e + (size_t)(((i0 * 9 + b) * 9 + a)) * 23;
                    float acc = 0.f;
                    if (a == b) { for (int p = 0; p < 23; ++p) acc += ua[p] * w[p]; }
                    else        { for (int p = 0; p < 23; ++p) acc += (ua[p] + ub[p]) * w[p]; }
                    emit(k++, acc);
                }
            float w2[4];
#pragma unroll
            for (int p = 0; p < 4; ++p) w2[p] = w2_0e[(s * 4 + p) * CC + c];
#pragma unroll 1
            for (int j = 0; j < 9; ++j) {
                const float* u = u2_0e + (size_t)((i0 * 9 + j)) * 4;
                float acc = 0.f;
                for (int p = 0; p < 4; ++p) acc += u[p] * w2[p];
                emit(45 + j, acc);
            }
        }
    } else if (row < 40) {
        for (int k = 0; k < 45; ++k) emit(k, 0.f);
        for (int k = 54; k < 64; ++k) emit(k, 0.f);
        int z = row - 36;
        if (z < 3) {
            float wv = w1_1o[s * CC + c];
#pragma unroll 1
            for (int i = 0; i < 9; ++i) emit(45 + i, u1_1o[z * 9 + i] * wv);
        } else {
            float wv = w1_0e[s * CC + c];
#pragma unroll 1
            for (int i = 0; i < 9; ++i) emit(45 + i, u1_0e[i] * wv);
        }
    } else {
        for (int k = 0; k < 64; ++k) emit(k, 0.f);
    }
}

// ---------------- prep: gk and lin as B-fragment streams (bf16) ----------------
__global__ __launch_bounds__(256) void k_prepf(
    const float* __restrict__ gk, const float* __restrict__ lin0,
    const float* __restrict__ lin1, u16* __restrict__ gkf, u16* __restrict__ linf) {
    int b = blockIdx.x, t = threadIdx.x, lane = t & 63, ck = t >> 6;
    if (b < 160) {
        int s = b >> 4, kt = b & 15;
        int k = kt * 16 + (lane & 15);
        u16* dst = gkf + (((size_t)b * 4 + ck) * 64 + lane) * 8;
        const float* src = gk + (size_t)s * CC * 256;
#pragma unroll
        for (int e = 0; e < 8; ++e) {
            int c = ck * 32 + ((lane >> 4) & 3) * 8 + e;
            dst[e] = bf16rne(src[c * 256 + k]);
        }
    } else {
        int bb = b - 160;            // part*8 + kt
        int kt = bb & 7;
        int k = kt * 16 + (lane & 15);
        const float* src = (bb >> 3) ? lin1 : lin0;
        u16* dst = linf + (((size_t)bb * 4 + ck) * 64 + lane) * 8;
#pragma unroll
        for (int e = 0; e < 8; ++e) {
            int c = ck * 32 + ((lane >> 4) & 3) * 8 + e;
            dst[e] = bf16rne(src[c * CC + k]);
        }
    }
}

// ---------------- symmetric contraction via MFMA ----------------
// block = 1024-node segment x 1 channel, 256 thr, 16 subtiles of 64 nodes.
// A-frags in registers; order in LDS; next subtile's x prefetched into regs
// during the MFMA phase (loads drain at the phase-end barrier).
__global__ __launch_bounds__(256) void k_contract(
    const float* __restrict__ nf, const int* __restrict__ order,
    const int* __restrict__ blk_sp, const u16* __restrict__ af_g,
    float* __restrict__ f0t, float* __restrict__ f1t) {
    int seg = blockIdx.x;                // 0..19
    int c = blockIdx.y;
    int s = blk_sp[seg];
    if (s < 0) return;

    __shared__ __align__(16) u16 afl[AFRAG_U16];      // 6 KB
    __shared__ int ordl[NPB];                         // 4 KB
    __shared__ float xl[64 * 13];                     // 3.3 KB
    __shared__ __align__(16) unsigned yl[64 * 40];    // 10.2 KB (swizzled)
    __shared__ float Bl[4 * 688];                     // 11 KB

    int tid = threadIdx.x;
    int lane = tid & 63, wave = tid >> 6;

    // stage A-fragments + order
    {
        const uint4* ag = (const uint4*)(af_g + (size_t)(c * SS + s) * AFRAG_U16);
        uint4* al = (uint4*)afl;
        al[tid] = ag[tid];
        if (tid < 128) al[256 + tid] = ag[256 + tid];
        const int* ob = order + seg * NPB;
        for (int i = tid; i < NPB; i += 256) ordl[i] = ob[i];
    }
    __syncthreads();

    bf16x8 areg0, areg1, areg2, areg3, areg4, areg5;
    {
        const bf16x8* afv = (const bf16x8*)afl;
        areg0 = afv[0 * 64 + lane]; areg1 = afv[1 * 64 + lane];
        areg2 = afv[2 * 64 + lane]; areg3 = afv[3 * 64 + lane];
        areg4 = afv[4 * 64 + lane]; areg5 = afv[5 * 64 + lane];
    }

    int n16 = lane & 15, g = lane >> 4;
    int myn = wave * 16 + n16;
    int permR = (myn & 7) ^ (myn >> 3);
    int permW = (lane & 7) ^ (lane >> 3);
    float* bw = &Bl[wave * 688];

    // prefetch subtile 0 x into regs
    float pf0 = 0.f, pf1 = 0.f, pf2 = 0.f;
    {
        int n = ordl[lane];
        if (n >= 0) {
            const float* r = nf + (size_t)n * 1152;
            if (wave == 0)      { pf0 = r[c]; }
            else if (wave == 1) { pf0 = r[128 + c * 3]; pf1 = r[128 + c * 3 + 1]; pf2 = r[128 + c * 3 + 2]; }
            else if (wave == 2) { pf0 = r[512 + c * 5]; pf1 = r[512 + c * 5 + 1]; }
            else                { pf0 = r[512 + c * 5 + 2]; pf1 = r[512 + c * 5 + 3]; pf2 = r[512 + c * 5 + 4]; }
        }
    }

#pragma unroll 1
    for (int sub = 0; sub < 16; ++sub) {
        // commit prefetched x to LDS
        if (wave == 0)      { xl[lane * 13 + 0] = pf0; }
        else if (wave == 1) { xl[lane * 13 + 1] = pf0; xl[lane * 13 + 2] = pf1; xl[lane * 13 + 3] = pf2; }
        else if (wave == 2) { xl[lane * 13 + 4] = pf0; xl[lane * 13 + 5] = pf1; }
        else                { xl[lane * 13 + 6] = pf0; xl[lane * 13 + 7] = pf1; xl[lane * 13 + 8] = pf2; }
        __syncthreads();

        // build y for node=lane, slots [16*wave, 16*wave+16), swizzled rows
        {
            float xr[9];
#pragma unroll
            for (int i = 0; i < 9; ++i) xr[i] = xl[lane * 13 + i];
#pragma unroll
            for (int w4 = 0; w4 < 4; ++w4) {
                if (wave == w4) {
                    unsigned pk[8];
#pragma unroll
                    for (int jj = 0; jj < 8; ++jj) {
                        const int s0 = w4 * 16 + 2 * jj, s1 = s0 + 1;
                        float v0 = (s0 < 45) ? xr[PA[s0]] * xr[PB[s0]]
                                 : ((s0 < 54) ? xr[s0 - 45] : 0.f);
                        float v1 = (s1 < 45) ? xr[PA[s1]] * xr[PB[s1]]
                                 : ((s1 < 54) ? xr[s1 - 45] : 0.f);
                        pk[jj] = (unsigned)bf16rne(v0) | ((unsigned)bf16rne(v1) << 16);
                    }
                    uint4 q0 = {pk[0], pk[1], pk[2], pk[3]};
                    uint4 q1 = {pk[4], pk[5], pk[6], pk[7]};
                    *(uint4*)&yl[lane * 40 + 4 * ((2 * w4) ^ permW)] = q0;
                    *(uint4*)&yl[lane * 40 + 4 * ((2 * w4 + 1) ^ permW)] = q1;
                }
            }
        }
        __syncthreads();

        // issue next subtile's x loads NOW — they drain at the barrier below,
        // hidden under the MFMA + epilogue phase.
        pf0 = 0.f; pf1 = 0.f; pf2 = 0.f;
        if (sub < 15) {
            int n = ordl[(sub + 1) * 64 + lane];
            if (n >= 0) {
                const float* r = nf + (size_t)n * 1152;
                if (wave == 0)      { pf0 = r[c]; }
                else if (wave == 1) { pf0 = r[128 + c * 3]; pf1 = r[128 + c * 3 + 1]; pf2 = r[128 + c * 3 + 2]; }
                else if (wave == 2) { pf0 = r[512 + c * 5]; pf1 = r[512 + c * 5 + 1]; }
                else                { pf0 = r[512 + c * 5 + 2]; pf1 = r[512 + c * 5 + 3]; pf2 = r[512 + c * 5 + 4]; }
            }
        }

        // MFMA
        bf16x8 yf0 = *(const bf16x8*)&yl[myn * 40 + 4 * (g ^ permR)];
        bf16x8 yf1 = *(const bf16x8*)&yl[myn * 40 + 4 * ((4 + g) ^ permR)];

        f32x4 acc0 = {0.f, 0.f, 0.f, 0.f}, acc1 = acc0, acc2 = acc0;
        acc0 = __builtin_amdgcn_mfma_f32_16x16x32_bf16(areg0, yf0, acc0, 0, 0, 0);
        acc0 = __builtin_amdgcn_mfma_f32_16x16x32_bf16(areg1, yf1, acc0, 0, 0, 0);
        acc1 = __builtin_amdgcn_mfma_f32_16x16x32_bf16(areg2, yf0, acc1, 0, 0, 0);
        acc1 = __builtin_amdgcn_mfma_f32_16x16x32_bf16(areg3, yf1, acc1, 0, 0, 0);
        acc2 = __builtin_amdgcn_mfma_f32_16x16x32_bf16(areg4, yf0, acc2, 0, 0, 0);
        acc2 = __builtin_amdgcn_mfma_f32_16x16x32_bf16(areg5, yf1, acc2, 0, 0, 0);

        // B scatter rows 0..39 only (R5 overflow lesson)
#pragma unroll
        for (int r = 0; r < 4; ++r) bw[n16 * 43 + 0 * 16 + g * 4 + r] = acc0[r];
#pragma unroll
        for (int r = 0; r < 4; ++r) bw[n16 * 43 + 1 * 16 + g * 4 + r] = acc1[r];
        if (g < 2) {
#pragma unroll
            for (int r = 0; r < 4; ++r) bw[n16 * 43 + 2 * 16 + g * 4 + r] = acc2[r];
        }

        float val = bw[n16 * 43 + 36 + g];
#pragma unroll
        for (int i = 0; i < 9; ++i) val += bw[n16 * 43 + g * 9 + i] * xl[myn * 13 + i];

        int pos = seg * NPB + sub * 64 + myn;
        if (g == 3) f0t[(size_t)c * NPAD + pos] = val;
        else        f1t[(size_t)(c * 3 + g) * NPAD + pos] = val;
        __syncthreads();   // xl/yl reuse next subtile; pf loads drain here
    }
}

// ---------------- fused gate + equivariant linear (MFMA) ----------------
#define GSTR 264
__global__ __launch_bounds__(256) void k_post(
    const float* __restrict__ f0t, const float* __restrict__ f1t,
    const u16* __restrict__ gkf, const u16* __restrict__ linf,
    const float* __restrict__ gb, const int* __restrict__ order,
    const int* __restrict__ blk_sp, float* __restrict__ out) {
    int tile = blockIdx.x;
    int s = blk_sp[tile >> 4];
    if (s < 0) return;
    int p0 = tile * 64;

    __shared__ __align__(16) u16 frag[4][4][64][8];   // 16 KB (A1, then A2)
    __shared__ __align__(16) u16 gate_l[64 * GSTR];   // 33 KB
    __shared__ int ord[64];

    int t = threadIdx.x, lane = t & 63, w = t >> 6;
    int l15 = lane & 15, lg = lane >> 4;
    if (t < 64) ord[t] = order[p0 + t];

    // stage A1 = scal (f0) bf16 fragments
#pragma unroll 1
    for (int it = 0; it < 32; ++it) {
        int posn = t & 63;
        int c = (t >> 6) + 4 * it;
        float v = f0t[(size_t)c * NPAD + p0 + posn];
        frag[posn >> 4][c >> 5][((c >> 3) & 3) * 16 + (posn & 15)][c & 7] = bf16rne(v);
    }
    __syncthreads();

    // GEMM1: gate[pos][k] = bias + sum_c scal[pos][c]*gk[c][k]
#pragma unroll 1
    for (int kt = 0; kt < 16; ++kt) {
        float bias = gb[s * 256 + kt * 16 + l15];
        f32x4 acc = {bias, bias, bias, bias};
#pragma unroll
        for (int ck = 0; ck < 4; ++ck) {
            bf16x8 a = *(const bf16x8*)&frag[w][ck][lane][0];
            bf16x8 b = *(const bf16x8*)&gkf[(((size_t)(s * 16 + kt)) * 4 + ck) * 512 + lane * 8];
            acc = __builtin_amdgcn_mfma_f32_16x16x32_bf16(a, b, acc, 0, 0, 0);
        }
#pragma unroll
        for (int r = 0; r < 4; ++r) {
            int posn = w * 16 + lg * 4 + r;
            gate_l[posn * GSTR + kt * 16 + l15] = bf16rne(acc[r]);
        }
    }
    __syncthreads();

    const float INV = 0.08838834764831845f;   // 1/sqrt(128)

    // GEMM2: p=0 -> f0*gate[:, :128] @ lin0 ; p=1..3 -> f1z*gate[:,128:] @ lin1
#pragma unroll 1
    for (int p = 0; p < 4; ++p) {
        // build A2 fragments
#pragma unroll 1
        for (int it = 0; it < 4; ++it) {
            int rr = it * 256 + t;                 // 0..1023
            int pt = rr >> 8, ck = (rr >> 6) & 3, l2 = rr & 63;
            int posn = pt * 16 + (l2 & 15);
            int cb = ck * 32 + (l2 >> 4) * 8;
            u16 res[8];
            if (p == 0) {
                bf16x8 a1 = *(const bf16x8*)&frag[pt][ck][l2][0];
                const u16* gp = &gate_l[posn * GSTR + cb];
#pragma unroll
                for (int e = 0; e < 8; ++e)
                    res[e] = bf16rne(bf2f((u16)a1[e]) * bf2f(gp[e]));
            } else {
                int z = p - 1;
                const u16* gp = &gate_l[posn * GSTR + 128 + cb];
#pragma unroll
                for (int e = 0; e < 8; ++e) {
                    float fv = f1t[((size_t)(cb + e) * 3 + z) * NPAD + p0 + posn];
                    res[e] = bf16rne(fv * bf2f(gp[e]));
                }
            }
            uint4 uv;
            uv.x = (unsigned)res[0] | ((unsigned)res[1] << 16);
            uv.y = (unsigned)res[2] | ((unsigned)res[3] << 16);
            uv.z = (unsigned)res[4] | ((unsigned)res[5] << 16);
            uv.w = (unsigned)res[6] | ((unsigned)res[7] << 16);
            *(uint4*)&frag[pt][ck][l2][0] = uv;
        }
        __syncthreads();

        int lbase = (p == 0) ? 0 : 8;
#pragma unroll 1
        for (int kt = 0; kt < 8; ++kt) {
            f32x4 acc = {0.f, 0.f, 0.f, 0.f};
#pragma unroll
            for (int ck = 0; ck < 4; ++ck) {
                bf16x8 a = *(const bf16x8*)&frag[w][ck][lane][0];
                bf16x8 b = *(const bf16x8*)&linf[(((size_t)(lbase + kt)) * 4 + ck) * 512 + lane * 8];
                acc = __builtin_amdgcn_mfma_f32_16x16x32_bf16(a, b, acc, 0, 0, 0);
            }
            int k = kt * 16 + l15;
            int kk = (p == 0) ? k : (128 + k * 3 + (p - 1));
#pragma unroll
            for (int r = 0; r < 4; ++r) {
                int posn = w * 16 + lg * 4 + r;
                int n = ord[posn];
                if (n >= 0) out[(size_t)n * 512 + kk] = acc[r] * INV;
            }
        }
        __syncthreads();
    }
}

// ---------------------------------------------------------------------------
extern "C" void kernel_launch(void* const* d_in, const int* in_sizes, int n_in,
                              void* d_out, int out_size, void* d_ws, size_t ws_size,
                              hipStream_t stream) {
    const float* nf    = (const float*)d_in[0];
    const int*   sp    = (const int*)  d_in[1];
    const float* u1_0e = (const float*)d_in[2];
    const float* u2_0e = (const float*)d_in[3];
    const float* u3_0e = (const float*)d_in[4];
    const float* u1_1o = (const float*)d_in[5];
    const float* u2_1o = (const float*)d_in[6];
    const float* u3_1o = (const float*)d_in[7];
    const float* w1_0e = (const float*)d_in[8];
    const float* w2_0e = (const float*)d_in[9];
    const float* w3_0e = (const float*)d_in[10];
    const float* w1_1o = (const float*)d_in[11];
    const float* w2_1o = (const float*)d_in[12];
    const float* w3_1o = (const float*)d_in[13];
    const float* gk    = (const float*)d_in[14];
    const float* gb    = (const float*)d_in[15];
    const float* lin0  = (const float*)d_in[16];
    const float* lin1  = (const float*)d_in[17];

    float* ws   = (float*)d_ws;
    u16*  af    = (u16*)(ws + OFF_AF);
    float* f0t  = ws + OFF_F0;
    float* f1t  = ws + OFF_F1;
    u16*  gkf   = (u16*)(ws + OFF_GKF);
    u16*  linf  = (u16*)(ws + OFF_LINF);
    int* order  = (int*)(ws + OFF_ORD);
    int* meta   = (int*)(ws + OFF_META);
    int* cursor = meta + 16;
    int* blk_sp = meta + 32;

    k_plan<<<1, 256, 0, stream>>>(sp, cursor, blk_sp, order);
    k_scatter<<<40, 256, 0, stream>>>(sp, cursor, order);
    dim3 gp(48, SS);
    k_prep2<<<gp, 128, 0, stream>>>(u1_0e, u2_0e, u3_0e, u1_1o, u2_1o, u3_1o,
                                    w1_0e, w2_0e, w3_0e, w1_1o, w2_1o, w3_1o, af);
    k_prepf<<<176, 256, 0, stream>>>(gk, lin0, lin1, gkf, linf);
    dim3 gm(MAXBLK, CC);
    k_contract<<<gm, 256, 0, stream>>>(nf, order, blk_sp, af, f0t, f1t);
    k_post<<<NPAD / 64, 256, 0, stream>>>(f0t, f1t, gkf, linf, gb, order, blk_sp,
                                          (float*)d_out);
}